// Round 16
// baseline (117532.202 us; speedup 1.0000x reference)
//
#include <hip/hip_runtime.h>
#include <hip/hip_bf16.h>

#define NN 10000
#define NE 160000

typedef _Float16 half8 __attribute__((ext_vector_type(8)));
typedef _Float16 half2v __attribute__((ext_vector_type(2)));
typedef float f32x4 __attribute__((ext_vector_type(4)));

__device__ __forceinline__ f32x4 mfma_f16(half8 a, half8 b, f32x4 c){
  return __builtin_amdgcn_mfma_f32_16x16x32_f16(a, b, c, 0, 0, 0);
}

#if defined(__has_builtin)
#if __has_builtin(__builtin_amdgcn_fdot2)
#define HAS_FDOT2 1
#endif
#endif

__device__ __forceinline__ float fdot2f(half2v a, half2v b, float c){
#ifdef HAS_FDOT2
  return __builtin_amdgcn_fdot2(a, b, c, false);
#else
  return c + (float)a[0]*(float)b[0] + (float)a[1]*(float)b[1];
#endif
}

// ---------------- utility ----------------
__global__ void zero_f32_kernel(float* __restrict__ p, int n){
  int i = blockIdx.x*blockDim.x + threadIdx.x;
  int st = gridDim.x*blockDim.x;
  for (; i < n; i += st) p[i] = 0.f;
}

__global__ void cast_f16_kernel(const float* __restrict__ a, _Float16* __restrict__ o, int n){
  int i = blockIdx.x*blockDim.x + threadIdx.x;
  int st = gridDim.x*blockDim.x;
  for (; i < n; i += st) o[i] = (_Float16)a[i];
}

// W1: [5][768][256] -> [5][256][768] f16 (both f and g)
__global__ void prep_w1t_kernel(const float* __restrict__ f, const float* __restrict__ g,
                                _Float16* __restrict__ fT, _Float16* __restrict__ gT){
  int i = blockIdx.x*256 + threadIdx.x;
  if (i >= 5*256*768) return;
  int l = i / (256*768); int r = i % (256*768);
  int c = r / 768; int k = r % 768;
  size_t s = (size_t)l*768*256 + (size_t)k*256 + c;
  fT[i] = (_Float16)f[s]; gT[i] = (_Float16)g[s];
}
// W2: [5][256][256] -> [5][256][256]T f16
__global__ void prep_w2t_kernel(const float* __restrict__ f, const float* __restrict__ g,
                                _Float16* __restrict__ fT, _Float16* __restrict__ gT){
  int i = blockIdx.x*256 + threadIdx.x;
  if (i >= 5*256*256) return;
  int l = i / (256*256); int r = i % (256*256);
  int c = r / 256; int k = r % 256;
  size_t s = (size_t)l*256*256 + (size_t)k*256 + c;
  fT[i] = (_Float16)f[s]; gT[i] = (_Float16)g[s];
}

// prepack whh stream: pk[((l*32+i)*768 + t)*8 + e] = (f16)whh[l][t][i*8+e]
__global__ void prep_whhPk_kernel(const float* __restrict__ whh, _Float16* __restrict__ pk){
  int idx = blockIdx.x*256 + threadIdx.x;   // 5*32*768 chunk-slots
  if (idx >= 5*32*768) return;
  int l = idx / (32*768); int r = idx % (32*768);
  int i = r / 768; int t = r % 768;
  const float* s = whh + (size_t)l*768*256 + (size_t)t*256 + i*8;
  _Float16* d = pk + (size_t)idx*8;
  #pragma unroll
  for (int e = 0; e < 8; e++) d[e] = (_Float16)s[e];
}

// ---------------- counting sort of edges by dst ----------------
__global__ void hist_kernel(const int* __restrict__ dst, int* __restrict__ cnt){
  int e = blockIdx.x*256 + threadIdx.x;
  if (e < NE) atomicAdd(&cnt[dst[e]], 1);
}

__global__ __launch_bounds__(1024) void scan_off_kernel(const int* __restrict__ cnt, int* __restrict__ cur){
  __shared__ int sA[1024];
  const int t = threadIdx.x;
  int run = 0;
  for (int ch = 0; ch < 10; ++ch){
    int idx = ch*1024 + t;
    int v = (idx < NN) ? cnt[idx] : 0;
    sA[t] = v;
    __syncthreads();
    for (int o = 1; o < 1024; o <<= 1){
      int add = (t >= o) ? sA[t-o] : 0;
      __syncthreads();
      sA[t] += add;
      __syncthreads();
    }
    if (idx < NN) cur[idx] = run + sA[t] - v;
    run += sA[1023];
    __syncthreads();
  }
}

__global__ void scatter_kernel(const int* __restrict__ eidx, const float* __restrict__ ea,
                               int* __restrict__ cur, int* __restrict__ srcS,
                               int* __restrict__ dstS, float* __restrict__ eaS){
  int e = blockIdx.x*256 + threadIdx.x;
  if (e < NE){
    int d = eidx[NE + e];
    int p = atomicAdd(&cur[d], 1);
    srcS[p] = eidx[e];
    dstS[p] = d;
    eaS[p]  = ea[e];
  }
}

// ---------------- node embedding ----------------
__global__ __launch_bounds__(256) void embed_kernel(const float* __restrict__ x,
    const float* __restrict__ neW, const float* __restrict__ neb,
    float* __restrict__ hv, _Float16* __restrict__ hvf){
  __shared__ float sx[16*64];
  int rb = blockIdx.x*16, t = threadIdx.x;
  for (int i = t; i < 16*64; i += 256) sx[i] = x[(size_t)rb*64 + i];
  __syncthreads();
  float acc[16];
  float bb = neb[t];
  #pragma unroll
  for (int r = 0; r < 16; r++) acc[r] = bb;
  for (int c = 0; c < 64; c++){
    float w = neW[c*256 + t];
    #pragma unroll
    for (int r = 0; r < 16; r++) acc[r] += sx[r*64 + c]*w;
  }
  for (int r = 0; r < 16; r++){
    hv [(size_t)(rb+r)*256 + t] = acc[r];
    hvf[(size_t)(rb+r)*256 + t] = (_Float16)acc[r];
  }
}

// ---------------- edge MLP (f16 MFMA) ----------------
__global__ __launch_bounds__(256, 2) void edge_mlp_kernel(
    const _Float16* __restrict__ hvf, const float* __restrict__ eaS,
    const int* __restrict__ srcS, const int* __restrict__ dstS,
    const float* __restrict__ eeW, const float* __restrict__ eeb,
    const _Float16* __restrict__ fW1T, const float* __restrict__ fb1,
    const _Float16* __restrict__ fW2T, const float* __restrict__ fb2,
    const _Float16* __restrict__ gW1T, const float* __restrict__ gb1,
    const _Float16* __restrict__ gW2T, const float* __restrict__ gb2,
    float* __restrict__ agg)
{
  extern __shared__ char smem[];
  _Float16* sHid = (_Float16*)smem;             // [64][264] f16
  float* sProd = (float*)smem;                  // aliases sHid: [32][264] f32
  float* sEW  = (float*)(smem + 64*264*2);      // 256
  float* sEB  = sEW + 256;
  int*   sDst = (int*)(sEB + 256);              // 64

  const int tid = threadIdx.x;
  const int wave = tid >> 6, lane = tid & 63;
  const int l15 = lane & 15, l4 = lane >> 4;
  const int eb = blockIdx.x*64;
  if (tid < 256){ sEW[tid] = eeW[tid]; sEB[tid] = eeb[tid]; }
  if (tid < 64)  sDst[tid] = dstS[eb + tid];
  int dd[4], ss[4]; float ea[4];
  #pragma unroll
  for (int rt = 0; rt < 4; rt++){
    int e = eb + rt*16 + l15;
    dd[rt] = dstS[e]; ss[rt] = srcS[e]; ea[rt] = eaS[e];
  }
  __syncthreads();
  const int colw = wave*64;
  const f32x4 zf = {0.f, 0.f, 0.f, 0.f};

  f32x4 accM[4][4], accA[4][4];
  #pragma unroll
  for (int a_ = 0; a_ < 4; a_++)
    #pragma unroll
    for (int b_ = 0; b_ < 4; b_++){ accM[a_][b_] = zf; accA[a_][b_] = zf; }

  // ===== f branch =====
  {
    f32x4 acc[4][4];
    #pragma unroll
    for (int a_ = 0; a_ < 4; a_++)
      #pragma unroll
      for (int b_ = 0; b_ < 4; b_++) acc[a_][b_] = zf;
    #pragma unroll 1
    for (int kc = 0; kc < 24; ++kc){
      const int kk = kc*32 + l4*8;
      half8 aF[4];
      if (kc < 8){
        #pragma unroll
        for (int rt = 0; rt < 4; rt++) aF[rt] = *(const half8*)(hvf + (size_t)dd[rt]*256 + kk);
      } else if (kc < 16){
        #pragma unroll
        for (int rt = 0; rt < 4; rt++) aF[rt] = *(const half8*)(hvf + (size_t)ss[rt]*256 + (kk - 256));
      } else {
        const int q = kk - 512;
        #pragma unroll
        for (int rt = 0; rt < 4; rt++){
          half8 v;
          #pragma unroll
          for (int j = 0; j < 8; j++) v[j] = (_Float16)(ea[rt]*sEW[q+j] + sEB[q+j]);
          aF[rt] = v;
        }
      }
      half8 bF[4];
      #pragma unroll
      for (int ct = 0; ct < 4; ct++)
        bF[ct] = *(const half8*)(fW1T + (size_t)(colw + ct*16 + l15)*768 + kk);
      #pragma unroll
      for (int rt = 0; rt < 4; rt++)
        #pragma unroll
        for (int ct = 0; ct < 4; ct++)
          acc[rt][ct] = mfma_f16(aF[rt], bF[ct], acc[rt][ct]);
    }
    #pragma unroll
    for (int ct = 0; ct < 4; ct++){
      const int col = colw + ct*16 + l15;
      const float bb = fb1[col];
      #pragma unroll
      for (int rt = 0; rt < 4; rt++)
        #pragma unroll
        for (int ri = 0; ri < 4; ri++){
          int row = rt*16 + l4*4 + ri;
          sHid[row*264 + col] = (_Float16)fmaxf(acc[rt][ct][ri] + bb, 0.f);
        }
    }
    __syncthreads();
    #pragma unroll 1
    for (int kc = 0; kc < 8; ++kc){
      const int kk = kc*32 + l4*8;
      half8 aF[4], bF[4];
      #pragma unroll
      for (int rt = 0; rt < 4; rt++) aF[rt] = *(const half8*)(sHid + (rt*16 + l15)*264 + kk);
      #pragma unroll
      for (int ct = 0; ct < 4; ct++) bF[ct] = *(const half8*)(fW2T + (size_t)(colw + ct*16 + l15)*256 + kk);
      #pragma unroll
      for (int rt = 0; rt < 4; rt++)
        #pragma unroll
        for (int ct = 0; ct < 4; ct++)
          accM[rt][ct] = mfma_f16(aF[rt], bF[ct], accM[rt][ct]);
    }
    __syncthreads();
  }

  // ===== g branch =====
  {
    f32x4 acc[4][4];
    #pragma unroll
    for (int a_ = 0; a_ < 4; a_++)
      #pragma unroll
      for (int b_ = 0; b_ < 4; b_++) acc[a_][b_] = zf;
    #pragma unroll 1
    for (int kc = 0; kc < 24; ++kc){
      const int kk = kc*32 + l4*8;
      half8 aF[4];
      if (kc < 8){
        #pragma unroll
        for (int rt = 0; rt < 4; rt++) aF[rt] = *(const half8*)(hvf + (size_t)dd[rt]*256 + kk);
      } else if (kc < 16){
        #pragma unroll
        for (int rt = 0; rt < 4; rt++) aF[rt] = *(const half8*)(hvf + (size_t)ss[rt]*256 + (kk - 256));
      } else {
        const int q = kk - 512;
        #pragma unroll
        for (int rt = 0; rt < 4; rt++){
          half8 v;
          #pragma unroll
          for (int j = 0; j < 8; j++) v[j] = (_Float16)(ea[rt]*sEW[q+j] + sEB[q+j]);
          aF[rt] = v;
        }
      }
      half8 bF[4];
      #pragma unroll
      for (int ct = 0; ct < 4; ct++)
        bF[ct] = *(const half8*)(gW1T + (size_t)(colw + ct*16 + l15)*768 + kk);
      #pragma unroll
      for (int rt = 0; rt < 4; rt++)
        #pragma unroll
        for (int ct = 0; ct < 4; ct++)
          acc[rt][ct] = mfma_f16(aF[rt], bF[ct], acc[rt][ct]);
    }
    #pragma unroll
    for (int ct = 0; ct < 4; ct++){
      const int col = colw + ct*16 + l15;
      const float bb = gb1[col];
      #pragma unroll
      for (int rt = 0; rt < 4; rt++)
        #pragma unroll
        for (int ri = 0; ri < 4; ri++){
          int row = rt*16 + l4*4 + ri;
          sHid[row*264 + col] = (_Float16)fmaxf(acc[rt][ct][ri] + bb, 0.f);
        }
    }
    __syncthreads();
    #pragma unroll 1
    for (int kc = 0; kc < 8; ++kc){
      const int kk = kc*32 + l4*8;
      half8 aF[4], bF[4];
      #pragma unroll
      for (int rt = 0; rt < 4; rt++) aF[rt] = *(const half8*)(sHid + (rt*16 + l15)*264 + kk);
      #pragma unroll
      for (int ct = 0; ct < 4; ct++) bF[ct] = *(const half8*)(gW2T + (size_t)(colw + ct*16 + l15)*256 + kk);
      #pragma unroll
      for (int rt = 0; rt < 4; rt++)
        #pragma unroll
        for (int ct = 0; ct < 4; ct++)
          accA[rt][ct] = mfma_f16(aF[rt], bF[ct], accA[rt][ct]);
    }
    __syncthreads();
  }

  // ===== prod + segment-sum epilogue, two 32-row halves =====
  int cd = sDst[0]; float ac = 0.f;
  #pragma unroll 1
  for (int hf = 0; hf < 2; ++hf){
    #pragma unroll
    for (int ct = 0; ct < 4; ct++){
      const int col = colw + ct*16 + l15;
      const float bm = fb2[col], ba = gb2[col];
      #pragma unroll
      for (int rt2 = 0; rt2 < 2; rt2++){
        const int rt = hf*2 + rt2;
        #pragma unroll
        for (int ri = 0; ri < 4; ri++){
          int row = rt2*16 + l4*4 + ri;   // local row within half
          sProd[row*264 + col] = (accM[rt][ct][ri] + bm)*(accA[rt][ct][ri] + ba);
        }
      }
    }
    __syncthreads();
    for (int r = 0; r < 32; ++r){
      float v = sProd[r*264 + tid];
      int dr = sDst[hf*32 + r];
      if (dr != cd){ atomicAdd(&agg[(size_t)cd*256 + tid], ac); ac = 0.f; cd = dr; }
      ac += v;
    }
    __syncthreads();
  }
  atomicAdd(&agg[(size_t)cd*256 + tid], ac);
}

// ---------------- gi = [h_v, agg] @ wih^T + bih (f16 MFMA) ----------------
#define RB_GI 157
__global__ __launch_bounds__(256, 3) void gi_mfma_kernel(
    const _Float16* __restrict__ hvf, const _Float16* __restrict__ aggf,
    const _Float16* __restrict__ wihL, const float* __restrict__ bihL,
    float* __restrict__ gi)
{
  const int tid = threadIdx.x;
  const int wave = tid >> 6, lane = tid & 63, l15 = lane & 15, l4 = lane >> 4;
  const int rblk = blockIdx.x % RB_GI;
  const int cg   = blockIdx.x / RB_GI;
  const int rb = rblk*64;
  const int colw = cg*256 + wave*64;
  int rowc[4];
  #pragma unroll
  for (int rt = 0; rt < 4; rt++){ int r = rb + rt*16 + l15; rowc[rt] = (r < NN) ? r : NN-1; }
  const f32x4 zf = {0.f, 0.f, 0.f, 0.f};
  f32x4 acc[4][4];
  #pragma unroll
  for (int a_ = 0; a_ < 4; a_++)
    #pragma unroll
    for (int b_ = 0; b_ < 4; b_++) acc[a_][b_] = zf;
  #pragma unroll 1
  for (int kc = 0; kc < 16; ++kc){
    const int kk = kc*32 + l4*8;
    half8 aF[4], bF[4];
    if (kc < 8){
      #pragma unroll
      for (int rt = 0; rt < 4; rt++) aF[rt] = *(const half8*)(hvf + (size_t)rowc[rt]*256 + kk);
    } else {
      #pragma unroll
      for (int rt = 0; rt < 4; rt++) aF[rt] = *(const half8*)(aggf + (size_t)rowc[rt]*256 + (kk - 256));
    }
    #pragma unroll
    for (int ct = 0; ct < 4; ct++)
      bF[ct] = *(const half8*)(wihL + (size_t)(colw + ct*16 + l15)*512 + kk);
    #pragma unroll
    for (int rt = 0; rt < 4; rt++)
      #pragma unroll
      for (int ct = 0; ct < 4; ct++)
        acc[rt][ct] = mfma_f16(aF[rt], bF[ct], acc[rt][ct]);
  }
  #pragma unroll
  for (int ct = 0; ct < 4; ct++){
    const int col = colw + ct*16 + l15;
    const float bb = bihL[col];
    #pragma unroll
    for (int rt = 0; rt < 4; rt++)
      #pragma unroll
      for (int ri = 0; ri < 4; ri++){
        int row = rb + rt*16 + l4*4 + ri;
        if (row < NN) gi[(size_t)row*768 + col] = acc[rt][ct][ri] + bb;
      }
  }
}

// ============ GRU scan variant A (fallback): r14 scan11, 512 thr, opaque regs =========
#define FOR16(M) M(0) M(1) M(2) M(3) M(4) M(5) M(6) M(7) M(8) M(9) M(10) M(11) M(12) M(13) M(14) M(15)
#define DECL_W(i) half8 wr##i, wz##i, wn##i;
#define LD8(dst, q, i) { float4 _a = (q)[2*(i)], _b = (q)[2*(i)+1]; \
  dst[0]=(_Float16)_a.x; dst[1]=(_Float16)_a.y; dst[2]=(_Float16)_a.z; dst[3]=(_Float16)_a.w; \
  dst[4]=(_Float16)_b.x; dst[5]=(_Float16)_b.y; dst[6]=(_Float16)_b.z; dst[7]=(_Float16)_b.w; }
#define LOAD_W(i) LD8(wr##i, q0, i) LD8(wz##i, q1, i) LD8(wn##i, q2, i)
#define OPQ(i) asm volatile("" : "+v"(wr##i), "+v"(wz##i), "+v"(wn##i));
#define SV(w, a, b) __builtin_shufflevector(w, w, a, b)
#define DOT_STEP(i) { half8 hh = ph[i]; \
  half2v h0 = SV(hh, 0, 1), h1 = SV(hh, 2, 3), h2 = SV(hh, 4, 5), h3 = SV(hh, 6, 7); \
  ar0 = fdot2f(SV(wr##i, 0, 1), h0, ar0); ar1 = fdot2f(SV(wr##i, 2, 3), h1, ar1); \
  ar0 = fdot2f(SV(wr##i, 4, 5), h2, ar0); ar1 = fdot2f(SV(wr##i, 6, 7), h3, ar1); \
  az0 = fdot2f(SV(wz##i, 0, 1), h0, az0); az1 = fdot2f(SV(wz##i, 2, 3), h1, az1); \
  az0 = fdot2f(SV(wz##i, 4, 5), h2, az0); az1 = fdot2f(SV(wz##i, 6, 7), h3, az1); \
  an0 = fdot2f(SV(wn##i, 0, 1), h0, an0); an1 = fdot2f(SV(wn##i, 2, 3), h1, an1); \
  an0 = fdot2f(SV(wn##i, 4, 5), h2, an0); an1 = fdot2f(SV(wn##i, 6, 7), h3, an1); }

__global__ __launch_bounds__(512, 1) void gru_scan11(
    const float* __restrict__ whhL, const float* __restrict__ bhhL,
    const float* __restrict__ gi, float* __restrict__ hv, _Float16* __restrict__ hvf)
{
  const int t = threadIdx.x;
  const int row = t & 255;
  const int hf  = t >> 8;
  const int c0  = hf*128;
  FOR16(DECL_W)
  {
    const float4* q0 = (const float4*)(whhL + (size_t)row*256 + c0);
    const float4* q1 = (const float4*)(whhL + (size_t)(256 + row)*256 + c0);
    const float4* q2 = (const float4*)(whhL + (size_t)(512 + row)*256 + c0);
    FOR16(LOAD_W)
  }
  FOR16(OPQ)
  const float br = bhhL[row], bz = bhhL[256 + row], bn = bhhL[512 + row];
  __shared__ __align__(16) _Float16 sH16[256];
  __shared__ float sP[6][256];
  float h = 0.f;
  if (t < 256) sH16[t] = (_Float16)0.f;
  float gr = 0.f, gz = 0.f, gn = 0.f;
  if (t < 256){ gr = gi[t]; gz = gi[256 + t]; gn = gi[512 + t]; }
  __syncthreads();
  #pragma unroll 1
  for (int step = 0; step < NN; ++step){
    float pr = 0.f, pz = 0.f, pn = 0.f;
    if (t < 256){
      const float* g = gi + (size_t)((step + 1 < NN) ? step + 1 : step)*768;
      pr = g[t]; pz = g[256 + t]; pn = g[512 + t];
    }
    const half8* ph = (const half8*)(sH16 + c0);
    float ar0 = 0.f, ar1 = 0.f, az0 = 0.f, az1 = 0.f, an0 = 0.f, an1 = 0.f;
    FOR16(DOT_STEP)
    sP[0 + hf][row] = ar0 + ar1;
    sP[2 + hf][row] = az0 + az1;
    sP[4 + hf][row] = an0 + an1;
    __syncthreads();
    if (t < 256){
      float hr = sP[0][t] + sP[1][t] + br;
      float hz = sP[2][t] + sP[3][t] + bz;
      float hn = sP[4][t] + sP[5][t] + bn;
      float r = 1.f/(1.f + __expf(-(gr + hr)));
      float z = 1.f/(1.f + __expf(-(gz + hz)));
      float xx = gn + r*hn;
      xx = fminf(fmaxf(xx, -15.f), 15.f);
      float e2 = __expf(2.f*xx);
      float n = (e2 - 1.f)/(e2 + 1.f);
      h = n + z*(h - n);
      hv [(size_t)step*256 + t] = h;
      hvf[(size_t)step*256 + t] = (_Float16)h;
      sH16[t] = (_Float16)h;
      gr = pr; gz = pz; gn = pn;
    }
    __syncthreads();
  }
}

// ============ GRU scan variant B: LDS-hybrid stream (n-gate in LDS) ==================
// Stream bound measured at ~427 GB/s/CU from L2 (r14/r15 agree). Cut bytes/step
// 384->256 KB by holding wn (rows 512..767, 128 KB f16) in LDS, XOR-swizzled
// (chunk j at j^(row&7); 8-way b128 conflict runs on the LDS pipe, hidden under
// the VMEM stream). Rows 0..511 stream via r15's pipelined coalesced path.
// Dynamic LDS = 131072(wn) + 3072(sGH) + 512(sH16) = 134656 B (needs attribute).
#define SVv(w, a, b) __builtin_shufflevector(w, w, a, b)
#define DOT8(w, h, acc) { \
  acc = fdot2f(SVv(w,0,1), SVv(h,0,1), acc); acc = fdot2f(SVv(w,2,3), SVv(h,2,3), acc); \
  acc = fdot2f(SVv(w,4,5), SVv(h,4,5), acc); acc = fdot2f(SVv(w,6,7), SVv(h,6,7), acc); }
#define LDPK(i) (*(const half8*)(pk + ((size_t)(i)*768 + t)*8))
#define PHASE(p, C0, C1, C2, C3, N0, N1, N2, N3) { \
  if ((p) < 7){ N0 = LDPK(4*(p)+4); N1 = LDPK(4*(p)+5); N2 = LDPK(4*(p)+6); N3 = LDPK(4*(p)+7); } \
  half8 h0 = ph[4*(p)+0], h1 = ph[4*(p)+1], h2 = ph[4*(p)+2], h3 = ph[4*(p)+3]; \
  DOT8(C0, h0, a0) DOT8(C1, h1, a1) DOT8(C2, h2, a2) DOT8(C3, h3, a3) }

__global__ __launch_bounds__(768, 1) void gru_scan13(
    const _Float16* __restrict__ pk,     // prepacked whh stream: [32][768][8] f16
    const float* __restrict__ whhL,      // raw whh layer (n-gate preload)
    const float* __restrict__ bhhL,
    const float* __restrict__ gi, float* __restrict__ hv, _Float16* __restrict__ hvf)
{
  extern __shared__ char sm[];
  half8* wnL = (half8*)sm;                               // [256*32] chunks, swizzled
  float* sGH = (float*)(sm + 131072);                    // 768
  _Float16* sH16 = (_Float16*)(sm + 131072 + 3072);      // 256
  const int t = threadIdx.x;   // gate-row t
  // one-time preload of n-gate (rows 512..767) into LDS, chunk j -> j^(row&7)
  for (int idx = t; idx < 256*32; idx += 768){
    int row = idx >> 5, j = idx & 31;
    const float* s = whhL + (size_t)(512 + row)*256 + j*8;
    half8 v;
    #pragma unroll
    for (int e = 0; e < 8; e++) v[e] = (_Float16)s[e];
    wnL[(row << 5) | (j ^ (row & 7))] = v;
  }
  const float bh = bhhL[t];
  float h = 0.f;
  if (t < 256) sH16[t] = (_Float16)0.f;
  float gr = 0.f, gz = 0.f, gn = 0.f;
  if (t < 256){ gr = gi[t]; gz = gi[256 + t]; gn = gi[512 + t]; }
  __syncthreads();
  const bool isn = (t >= 512);     // wave-uniform (waves 8..11)
  const int nrow = t - 512;
  #pragma unroll 1
  for (int step = 0; step < NN; ++step){
    float pr = 0.f, pz = 0.f, pn = 0.f;
    if (t < 256){
      const float* g = gi + (size_t)((step + 1 < NN) ? step + 1 : step)*768;
      pr = g[t]; pz = g[256 + t]; pn = g[512 + t];
    }
    const half8* ph = (const half8*)sH16;
    float a0 = 0.f, a1 = 0.f, a2 = 0.f, a3 = 0.f;
    if (!isn){
      half8 Wa0 = LDPK(0), Wa1 = LDPK(1), Wa2 = LDPK(2), Wa3 = LDPK(3);
      half8 Wb0, Wb1, Wb2, Wb3;
      PHASE(0, Wa0, Wa1, Wa2, Wa3, Wb0, Wb1, Wb2, Wb3)
      PHASE(1, Wb0, Wb1, Wb2, Wb3, Wa0, Wa1, Wa2, Wa3)
      PHASE(2, Wa0, Wa1, Wa2, Wa3, Wb0, Wb1, Wb2, Wb3)
      PHASE(3, Wb0, Wb1, Wb2, Wb3, Wa0, Wa1, Wa2, Wa3)
      PHASE(4, Wa0, Wa1, Wa2, Wa3, Wb0, Wb1, Wb2, Wb3)
      PHASE(5, Wb0, Wb1, Wb2, Wb3, Wa0, Wa1, Wa2, Wa3)
      PHASE(6, Wa0, Wa1, Wa2, Wa3, Wb0, Wb1, Wb2, Wb3)
      PHASE(7, Wb0, Wb1, Wb2, Wb3, Wa0, Wa1, Wa2, Wa3)
    } else {
      const half8* wr = wnL + (nrow << 5);
      const int sw = nrow & 7;
      #pragma unroll
      for (int j = 0; j < 32; j += 4){
        half8 w0 = wr[(j+0) ^ sw];
        half8 w1 = wr[(j+1) ^ sw];
        half8 w2 = wr[(j+2) ^ sw];
        half8 w3 = wr[(j+3) ^ sw];
        half8 h0 = ph[j+0], h1 = ph[j+1], h2 = ph[j+2], h3 = ph[j+3];
        DOT8(w0, h0, a0) DOT8(w1, h1, a1) DOT8(w2, h2, a2) DOT8(w3, h3, a3)
      }
    }
    sGH[t] = (a0 + a1) + (a2 + a3) + bh;
    __syncthreads();
    if (t < 256){
      float hr = sGH[t], hz = sGH[256 + t], hn = sGH[512 + t];
      float r = 1.f/(1.f + __expf(-(gr + hr)));
      float z = 1.f/(1.f + __expf(-(gz + hz)));
      float xx = gn + r*hn;
      xx = fminf(fmaxf(xx, -15.f), 15.f);
      float e2 = __expf(2.f*xx);
      float n = (e2 - 1.f)/(e2 + 1.f);
      h = n + z*(h - n);
      hv [(size_t)step*256 + t] = h;
      hvf[(size_t)step*256 + t] = (_Float16)h;
      sH16[t] = (_Float16)h;
      gr = pr; gz = pz; gn = pn;
    }
    __syncthreads();
  }
}

// ---------------- heads ----------------
__global__ __launch_bounds__(256) void ge_sum_kernel(const float* __restrict__ hv, float* __restrict__ ge){
  int rb = blockIdx.x*40, t = threadIdx.x;
  float s = 0.f;
  for (int i = 0; i < 40; i++) s += hv[(size_t)(rb + i)*256 + t];
  atomicAdd(&ge[t], s);
}

__global__ void finalize_kernel(const float* __restrict__ ge, const float* __restrict__ hv,
                                const int* __restrict__ vt, float* __restrict__ gem, float* __restrict__ hvt){
  int t = threadIdx.x;
  gem[t] = ge[t]*(1.0f/NN);
  hvt[t] = hv[(size_t)vt[0]*256 + t];
}

__global__ __launch_bounds__(256) void base_np_kernel(const float* __restrict__ gem,
    const float* __restrict__ npW1, const float* __restrict__ npb1, float* __restrict__ bnp){
  __shared__ float sg[256];
  int t = threadIdx.x; sg[t] = gem[t]; __syncthreads();
  float a = npb1[t];
  for (int c = 0; c < 256; c++) a += sg[c]*npW1[c*256 + t];
  bnp[t] = a;
}

__global__ __launch_bounds__(256) void base_al_kernel(const float* __restrict__ gem,
    const float* __restrict__ hvt, const float* __restrict__ aW1,
    const float* __restrict__ ab1, float* __restrict__ bal){
  __shared__ float sg[256], sv[256];
  int t = threadIdx.x; sg[t] = gem[t]; sv[t] = hvt[t]; __syncthreads();
  float a = ab1[t];
  for (int c = 0; c < 256; c++) a += sg[c]*aW1[c*256 + t];
  for (int c = 0; c < 256; c++) a += sv[c]*aW1[(256 + c)*256 + t];
  bal[t] = a;
}

__global__ __launch_bounds__(256) void node_pred_kernel(const float* __restrict__ hv,
    const float* __restrict__ bnp, const float* __restrict__ npW1,
    const float* __restrict__ npW2, const float* __restrict__ npb2,
    float* __restrict__ outPV){
  __shared__ float sHv[16*256];
  __shared__ float sHid[16*257];
  __shared__ float sLg[16*10];
  int rb = blockIdx.x*16, t = threadIdx.x;
  for (int i = t; i < 4096; i += 256) sHv[i] = hv[(size_t)rb*256 + i];
  __syncthreads();
  float acc[16]; float b = bnp[t];
  #pragma unroll
  for (int r = 0; r < 16; r++) acc[r] = b;
  for (int c = 0; c < 256; c++){
    float w = npW1[(256 + c)*256 + t];
    #pragma unroll
    for (int r = 0; r < 16; r++) acc[r] += sHv[r*256 + c]*w;
  }
  for (int r = 0; r < 16; r++) sHid[r*257 + t] = fmaxf(acc[r], 0.f);
  __syncthreads();
  {
    int r = t >> 4, u = t & 15;
    if (u < 10){
      float a = npb2[u];
      for (int c = 0; c < 256; c++) a += sHid[r*257 + c]*npW2[c*10 + u];
      sLg[r*10 + u] = a;
    }
  }
  __syncthreads();
  if (t < 16){
    float mx = -1e30f;
    for (int u = 0; u < 10; u++) mx = fmaxf(mx, sLg[t*10 + u]);
    float s = 0.f, e[10];
    for (int u = 0; u < 10; u++){ e[u] = __expf(sLg[t*10 + u] - mx); s += e[u]; }
    float inv = 1.f/s;
    for (int u = 0; u < 10; u++) outPV[(size_t)(rb + t)*10 + u] = e[u]*inv;
  }
}

__global__ __launch_bounds__(256) void alphas_kernel(const float* __restrict__ hv,
    const float* __restrict__ bal, const float* __restrict__ aW1,
    const float* __restrict__ aW2, const float* __restrict__ ab2,
    float* __restrict__ alsum){
  __shared__ float sHv[16*256];
  __shared__ float sHid[16*257];
  __shared__ float sAv[16*20];
  int rb = blockIdx.x*16, t = threadIdx.x;
  for (int i = t; i < 4096; i += 256) sHv[i] = hv[(size_t)rb*256 + i];
  __syncthreads();
  float acc[16]; float b = bal[t];
  #pragma unroll
  for (int r = 0; r < 16; r++) acc[r] = b;
  for (int c = 0; c < 256; c++){
    float w = aW1[(512 + c)*256 + t];
    #pragma unroll
    for (int r = 0; r < 16; r++) acc[r] += sHv[r*256 + c]*w;
  }
  for (int r = 0; r < 16; r++) sHid[r*257 + t] = fmaxf(acc[r], 0.f);
  __syncthreads();
  {
    int r = t >> 4, k = t & 15;
    float a = ab2[k];
    for (int c = 0; c < 256; c++) a += sHid[r*257 + c]*aW2[c*20 + k];
    sAv[r*20 + k] = a;
    if (k < 4){
      int k2 = 16 + k;
      float a2 = ab2[k2];
      for (int c = 0; c < 256; c++) a2 += sHid[r*257 + c]*aW2[c*20 + k2];
      sAv[r*20 + k2] = a2;
    }
  }
  __syncthreads();
  if (t < 20){
    float s = 0.f;
    for (int rr = 0; rr < 16; rr++) s += sAv[rr*20 + t];
    atomicAdd(&alsum[t], s);
  }
}

__global__ void alpha_softmax_kernel(const float* __restrict__ alsum, float* __restrict__ alph){
  if (threadIdx.x == 0){
    float mx = -1e30f;
    for (int k = 0; k < 20; k++) mx = fmaxf(mx, alsum[k]);
    float s = 0.f, e[20];
    for (int k = 0; k < 20; k++){ e[k] = __expf(alsum[k] - mx); s += e[k]; }
    for (int k = 0; k < 20; k++) alph[k] = e[k]/s;
  }
}

__global__ __launch_bounds__(256) void edge_pred_kernel(const float* __restrict__ hv,
    const float* __restrict__ epW1, const float* __restrict__ epb1,
    const float* __restrict__ epW2, const float* __restrict__ epb2,
    const float* __restrict__ alph, float* __restrict__ outPE){
  __shared__ float sHv[16*256];
  __shared__ float sHid[16*257];
  __shared__ float sLT[16*100];
  __shared__ float sPE[16*5];
  __shared__ float sAl[20];
  int rb = blockIdx.x*16, t = threadIdx.x;
  for (int i = t; i < 4096; i += 256) sHv[i] = hv[(size_t)rb*256 + i];
  if (t < 20) sAl[t] = alph[t];
  if (t < 80) sPE[t] = 0.f;
  __syncthreads();
  float acc[16]; float b = epb1[t];
  #pragma unroll
  for (int r = 0; r < 16; r++) acc[r] = b;
  for (int c = 0; c < 256; c++){
    float w = epW1[c*256 + t];
    #pragma unroll
    for (int r = 0; r < 16; r++) acc[r] += sHv[r*256 + c]*w;
  }
  for (int r = 0; r < 16; r++) sHid[r*257 + t] = fmaxf(acc[r], 0.f);
  __syncthreads();
  for (int p = 0; p < 7; p++){
    int idx = p*256 + t;
    if (idx < 1600){
      int r = idx/100, j = idx%100;
      float a = epb2[j];
      for (int c = 0; c < 256; c++) a += sHid[r*257 + c]*epW2[c*100 + j];
      sLT[r*100 + j] = a;
    }
  }
  __syncthreads();
  {
    int r = t >> 4, k = t & 15;
    for (int pass = 0; pass < 2; ++pass){
      int kk = pass ? (16 + k) : k;
      if (pass && k >= 4) break;
      float lt[5];
      #pragma unroll
      for (int net = 0; net < 5; net++) lt[net] = sLT[r*100 + net*20 + kk];
      float mx = lt[0];
      #pragma unroll
      for (int net = 1; net < 5; net++) mx = fmaxf(mx, lt[net]);
      float e[5], s = 0.f;
      #pragma unroll
      for (int net = 0; net < 5; net++){ e[net] = __expf(lt[net] - mx); s += e[net]; }
      float wgt = sAl[kk]/s;
      #pragma unroll
      for (int net = 0; net < 5; net++) atomicAdd(&sPE[r*5 + net], e[net]*wgt);
    }
  }
  __syncthreads();
  if (t < 80){
    int r = t/5, net = t%5;
    outPE[(size_t)(rb + r)*5 + net] = sPE[t];
  }
}

// ---------------- launch ----------------
extern "C" void kernel_launch(void* const* d_in, const int* in_sizes, int n_in,
                              void* d_out, int out_size, void* d_ws, size_t ws_size,
                              hipStream_t stream){
  const float* x    = (const float*)d_in[0];
  const float* edge_attr = (const float*)d_in[1];
  const float* neW  = (const float*)d_in[2];
  const float* neb  = (const float*)d_in[3];
  const float* eeW  = (const float*)d_in[4];
  const float* eeb  = (const float*)d_in[5];
  const float* fW1  = (const float*)d_in[6];
  const float* fb1  = (const float*)d_in[7];
  const float* fW2  = (const float*)d_in[8];
  const float* fb2  = (const float*)d_in[9];
  const float* gW1  = (const float*)d_in[10];
  const float* gb1  = (const float*)d_in[11];
  const float* gW2  = (const float*)d_in[12];
  const float* gb2  = (const float*)d_in[13];
  const float* wih  = (const float*)d_in[14];
  const float* whh  = (const float*)d_in[15];
  const float* bih  = (const float*)d_in[16];
  const float* bhh  = (const float*)d_in[17];
  const float* aW1  = (const float*)d_in[18];
  const float* ab1  = (const float*)d_in[19];
  const float* aW2  = (const float*)d_in[20];
  const float* ab2  = (const float*)d_in[21];
  const float* npW1 = (const float*)d_in[22];
  const float* npb1 = (const float*)d_in[23];
  const float* npW2 = (const float*)d_in[24];
  const float* npb2 = (const float*)d_in[25];
  const float* epW1 = (const float*)d_in[26];
  const float* epb1 = (const float*)d_in[27];
  const float* epW2 = (const float*)d_in[28];
  const float* epb2 = (const float*)d_in[29];
  const int*   eidx = (const int*)d_in[30];
  const int*   vt   = (const int*)d_in[31];

  char* ws = (char*)d_ws;
  size_t off_ = 0;
  auto alloc = [&](size_t b){ size_t r = off_; off_ += (b + 511) & ~(size_t)511; return r; };
  float*    hv    = (float*)   (ws + alloc((size_t)NN*256*4));
  _Float16* hvf   = (_Float16*)(ws + alloc((size_t)NN*256*2));
  float*    agg   = (float*)   (ws + alloc((size_t)NN*256*4));
  _Float16* aggf  = (_Float16*)(ws + alloc((size_t)NN*256*2));
  float*    gi    = (float*)   (ws + alloc((size_t)NN*768*4));
  _Float16* fW1T  = (_Float16*)(ws + alloc((size_t)5*256*768*2));
  _Float16* gW1T  = (_Float16*)(ws + alloc((size_t)5*256*768*2));
  _Float16* fW2T  = (_Float16*)(ws + alloc((size_t)5*256*256*2));
  _Float16* gW2T  = (_Float16*)(ws + alloc((size_t)5*256*256*2));
  _Float16* wihf  = (_Float16*)(ws + alloc((size_t)5*768*512*2));
  _Float16* whhPk = (_Float16*)(ws + alloc((size_t)5*32*768*8*2));
  int*      cnt   = (int*)     (ws + alloc((size_t)NN*4));
  int*      cur   = (int*)     (ws + alloc((size_t)NN*4));
  int*      srcS  = (int*)     (ws + alloc((size_t)NE*4));
  int*      dstS  = (int*)     (ws + alloc((size_t)NE*4));
  float*    eaS   = (float*)   (ws + alloc((size_t)NE*4));
  float*    ge    = (float*)   (ws + alloc(256*4));
  float*    gem   = (float*)   (ws + alloc(256*4));
  float*    hvt   = (float*)   (ws + alloc(256*4));
  float*    bnp   = (float*)   (ws + alloc(256*4));
  float*    bal   = (float*)   (ws + alloc(256*4));
  float*    alsum = (float*)   (ws + alloc(128));
  float*    alph  = (float*)   (ws + alloc(128));

  // d_out is FLOAT32: p_v [N,10] then p_e [N,5]
  float* outPV = (float*)d_out;
  float* outPE = outPV + (size_t)NN*10;

  // allow >64KB dynamic LDS for the hybrid scan (no-op if already permitted)
  (void)hipFuncSetAttribute((const void*)gru_scan13,
                            hipFuncAttributeMaxDynamicSharedMemorySize, 135168);
  (void)hipGetLastError();   // clear stale error state

  // weight prep (f16 transposed copies + prepacked whh stream)
  prep_w1t_kernel<<<3840, 256, 0, stream>>>(fW1, gW1, fW1T, gW1T);
  prep_w2t_kernel<<<1280, 256, 0, stream>>>(fW2, gW2, fW2T, gW2T);
  cast_f16_kernel<<<2048, 256, 0, stream>>>(wih, wihf, 5*768*512);
  prep_whhPk_kernel<<<480, 256, 0, stream>>>(whh, whhPk);

  // counting sort of edges by dst
  zero_f32_kernel<<<40, 256, 0, stream>>>((float*)cnt, NN);
  hist_kernel<<<625, 256, 0, stream>>>(eidx + NE, cnt);
  scan_off_kernel<<<1, 1024, 0, stream>>>(cnt, cur);
  scatter_kernel<<<625, 256, 0, stream>>>(eidx, edge_attr, cur, srcS, dstS, eaS);

  // embedding
  embed_kernel<<<625, 256, 0, stream>>>(x, neW, neb, hv, hvf);

  const size_t edge_lds = (size_t)64*264*2 + 2048 + 256;   // 36096 B
  const size_t gru_lds  = 131072 + 3072 + 512;             // 134656 B
  for (int l = 0; l < 5; ++l){
    zero_f32_kernel<<<2048, 256, 0, stream>>>(agg, NN*256);
    edge_mlp_kernel<<<2500, 256, edge_lds, stream>>>(hvf, eaS, srcS, dstS, eeW, eeb,
        fW1T + (size_t)l*256*768, fb1 + l*256, fW2T + (size_t)l*256*256, fb2 + l*256,
        gW1T + (size_t)l*256*768, gb1 + l*256, gW2T + (size_t)l*256*256, gb2 + l*256, agg);
    cast_f16_kernel<<<2048, 256, 0, stream>>>(agg, aggf, NN*256);
    gi_mfma_kernel<<<471, 256, 0, stream>>>(hvf, aggf, wihf + (size_t)l*768*512, bih + l*768, gi);
    gru_scan13<<<1, 768, gru_lds, stream>>>(whhPk + (size_t)l*32*768*8,
        whh + (size_t)l*768*256, bhh + l*768, gi, hv, hvf);
    if (hipGetLastError() != hipSuccess){
      // deterministic fallback (environment-dependent, not data-dependent)
      gru_scan11<<<1, 512, 0, stream>>>(whh + (size_t)l*768*256, bhh + l*768, gi, hv, hvf);
    }
  }

  // heads
  zero_f32_kernel<<<1, 256, 0, stream>>>(ge, 256);
  zero_f32_kernel<<<1, 64, 0, stream>>>(alsum, 32);
  ge_sum_kernel<<<250, 256, 0, stream>>>(hv, ge);
  finalize_kernel<<<1, 256, 0, stream>>>(ge, hv, vt, gem, hvt);
  base_np_kernel<<<1, 256, 0, stream>>>(gem, npW1, npb1, bnp);
  base_al_kernel<<<1, 256, 0, stream>>>(gem, hvt, aW1, ab1, bal);
  node_pred_kernel<<<625, 256, 0, stream>>>(hv, bnp, npW1, npW2, npb2, outPV);
  alphas_kernel<<<625, 256, 0, stream>>>(hv, bal, aW1, aW2, ab2, alsum);
  alpha_softmax_kernel<<<1, 64, 0, stream>>>(alsum, alph);
  edge_pred_kernel<<<625, 256, 0, stream>>>(hv, epW1, epb1, epW2, epb2, alph, outPE);
}

// Round 17
// 117370.764 us; speedup vs baseline: 1.0014x; 1.0014x over previous
//
#include <hip/hip_runtime.h>
#include <hip/hip_bf16.h>

#define NN 10000
#define NE 160000

typedef _Float16 half8 __attribute__((ext_vector_type(8)));
typedef _Float16 half2v __attribute__((ext_vector_type(2)));
typedef float f32x4 __attribute__((ext_vector_type(4)));

__device__ __forceinline__ f32x4 mfma_f16(half8 a, half8 b, f32x4 c){
  return __builtin_amdgcn_mfma_f32_16x16x32_f16(a, b, c, 0, 0, 0);
}

#if defined(__has_builtin)
#if __has_builtin(__builtin_amdgcn_fdot2)
#define HAS_FDOT2 1
#endif
#endif

__device__ __forceinline__ float fdot2f(half2v a, half2v b, float c){
#ifdef HAS_FDOT2
  return __builtin_amdgcn_fdot2(a, b, c, false);
#else
  return c + (float)a[0]*(float)b[0] + (float)a[1]*(float)b[1];
#endif
}

// ---------------- utility ----------------
__global__ void zero_f32_kernel(float* __restrict__ p, int n){
  int i = blockIdx.x*blockDim.x + threadIdx.x;
  int st = gridDim.x*blockDim.x;
  for (; i < n; i += st) p[i] = 0.f;
}

__global__ void cast_f16_kernel(const float* __restrict__ a, _Float16* __restrict__ o, int n){
  int i = blockIdx.x*blockDim.x + threadIdx.x;
  int st = gridDim.x*blockDim.x;
  for (; i < n; i += st) o[i] = (_Float16)a[i];
}

// W1: [5][768][256] -> [5][256][768] f16 (both f and g)
__global__ void prep_w1t_kernel(const float* __restrict__ f, const float* __restrict__ g,
                                _Float16* __restrict__ fT, _Float16* __restrict__ gT){
  int i = blockIdx.x*256 + threadIdx.x;
  if (i >= 5*256*768) return;
  int l = i / (256*768); int r = i % (256*768);
  int c = r / 768; int k = r % 768;
  size_t s = (size_t)l*768*256 + (size_t)k*256 + c;
  fT[i] = (_Float16)f[s]; gT[i] = (_Float16)g[s];
}
// W2: [5][256][256] -> [5][256][256]T f16
__global__ void prep_w2t_kernel(const float* __restrict__ f, const float* __restrict__ g,
                                _Float16* __restrict__ fT, _Float16* __restrict__ gT){
  int i = blockIdx.x*256 + threadIdx.x;
  if (i >= 5*256*256) return;
  int l = i / (256*256); int r = i % (256*256);
  int c = r / 256; int k = r % 256;
  size_t s = (size_t)l*256*256 + (size_t)k*256 + c;
  fT[i] = (_Float16)f[s]; gT[i] = (_Float16)g[s];
}

// prepack whh stream: pk[((l*32+i)*768 + t)*8 + e] = (f16)whh[l][t][i*8+e]
__global__ void prep_whhPk_kernel(const float* __restrict__ whh, _Float16* __restrict__ pk){
  int idx = blockIdx.x*256 + threadIdx.x;   // 5*32*768 chunk-slots
  if (idx >= 5*32*768) return;
  int l = idx / (32*768); int r = idx % (32*768);
  int i = r / 768; int t = r % 768;
  const float* s = whh + (size_t)l*768*256 + (size_t)t*256 + i*8;
  _Float16* d = pk + (size_t)idx*8;
  #pragma unroll
  for (int e = 0; e < 8; e++) d[e] = (_Float16)s[e];
}

// ---------------- counting sort of edges by dst ----------------
__global__ void hist_kernel(const int* __restrict__ dst, int* __restrict__ cnt){
  int e = blockIdx.x*256 + threadIdx.x;
  if (e < NE) atomicAdd(&cnt[dst[e]], 1);
}

__global__ __launch_bounds__(1024) void scan_off_kernel(const int* __restrict__ cnt, int* __restrict__ cur){
  __shared__ int sA[1024];
  const int t = threadIdx.x;
  int run = 0;
  for (int ch = 0; ch < 10; ++ch){
    int idx = ch*1024 + t;
    int v = (idx < NN) ? cnt[idx] : 0;
    sA[t] = v;
    __syncthreads();
    for (int o = 1; o < 1024; o <<= 1){
      int add = (t >= o) ? sA[t-o] : 0;
      __syncthreads();
      sA[t] += add;
      __syncthreads();
    }
    if (idx < NN) cur[idx] = run + sA[t] - v;
    run += sA[1023];
    __syncthreads();
  }
}

__global__ void scatter_kernel(const int* __restrict__ eidx, const float* __restrict__ ea,
                               int* __restrict__ cur, int* __restrict__ srcS,
                               int* __restrict__ dstS, float* __restrict__ eaS){
  int e = blockIdx.x*256 + threadIdx.x;
  if (e < NE){
    int d = eidx[NE + e];
    int p = atomicAdd(&cur[d], 1);
    srcS[p] = eidx[e];
    dstS[p] = d;
    eaS[p]  = ea[e];
  }
}

// ---------------- node embedding ----------------
__global__ __launch_bounds__(256) void embed_kernel(const float* __restrict__ x,
    const float* __restrict__ neW, const float* __restrict__ neb,
    float* __restrict__ hv, _Float16* __restrict__ hvf){
  __shared__ float sx[16*64];
  int rb = blockIdx.x*16, t = threadIdx.x;
  for (int i = t; i < 16*64; i += 256) sx[i] = x[(size_t)rb*64 + i];
  __syncthreads();
  float acc[16];
  float bb = neb[t];
  #pragma unroll
  for (int r = 0; r < 16; r++) acc[r] = bb;
  for (int c = 0; c < 64; c++){
    float w = neW[c*256 + t];
    #pragma unroll
    for (int r = 0; r < 16; r++) acc[r] += sx[r*64 + c]*w;
  }
  for (int r = 0; r < 16; r++){
    hv [(size_t)(rb+r)*256 + t] = acc[r];
    hvf[(size_t)(rb+r)*256 + t] = (_Float16)acc[r];
  }
}

// ---------------- edge MLP (f16 MFMA) ----------------
__global__ __launch_bounds__(256, 2) void edge_mlp_kernel(
    const _Float16* __restrict__ hvf, const float* __restrict__ eaS,
    const int* __restrict__ srcS, const int* __restrict__ dstS,
    const float* __restrict__ eeW, const float* __restrict__ eeb,
    const _Float16* __restrict__ fW1T, const float* __restrict__ fb1,
    const _Float16* __restrict__ fW2T, const float* __restrict__ fb2,
    const _Float16* __restrict__ gW1T, const float* __restrict__ gb1,
    const _Float16* __restrict__ gW2T, const float* __restrict__ gb2,
    float* __restrict__ agg)
{
  extern __shared__ char smem[];
  _Float16* sHid = (_Float16*)smem;             // [64][264] f16
  float* sProd = (float*)smem;                  // aliases sHid: [32][264] f32
  float* sEW  = (float*)(smem + 64*264*2);      // 256
  float* sEB  = sEW + 256;
  int*   sDst = (int*)(sEB + 256);              // 64

  const int tid = threadIdx.x;
  const int wave = tid >> 6, lane = tid & 63;
  const int l15 = lane & 15, l4 = lane >> 4;
  const int eb = blockIdx.x*64;
  if (tid < 256){ sEW[tid] = eeW[tid]; sEB[tid] = eeb[tid]; }
  if (tid < 64)  sDst[tid] = dstS[eb + tid];
  int dd[4], ss[4]; float ea[4];
  #pragma unroll
  for (int rt = 0; rt < 4; rt++){
    int e = eb + rt*16 + l15;
    dd[rt] = dstS[e]; ss[rt] = srcS[e]; ea[rt] = eaS[e];
  }
  __syncthreads();
  const int colw = wave*64;
  const f32x4 zf = {0.f, 0.f, 0.f, 0.f};

  f32x4 accM[4][4], accA[4][4];
  #pragma unroll
  for (int a_ = 0; a_ < 4; a_++)
    #pragma unroll
    for (int b_ = 0; b_ < 4; b_++){ accM[a_][b_] = zf; accA[a_][b_] = zf; }

  // ===== f branch =====
  {
    f32x4 acc[4][4];
    #pragma unroll
    for (int a_ = 0; a_ < 4; a_++)
      #pragma unroll
      for (int b_ = 0; b_ < 4; b_++) acc[a_][b_] = zf;
    #pragma unroll 1
    for (int kc = 0; kc < 24; ++kc){
      const int kk = kc*32 + l4*8;
      half8 aF[4];
      if (kc < 8){
        #pragma unroll
        for (int rt = 0; rt < 4; rt++) aF[rt] = *(const half8*)(hvf + (size_t)dd[rt]*256 + kk);
      } else if (kc < 16){
        #pragma unroll
        for (int rt = 0; rt < 4; rt++) aF[rt] = *(const half8*)(hvf + (size_t)ss[rt]*256 + (kk - 256));
      } else {
        const int q = kk - 512;
        #pragma unroll
        for (int rt = 0; rt < 4; rt++){
          half8 v;
          #pragma unroll
          for (int j = 0; j < 8; j++) v[j] = (_Float16)(ea[rt]*sEW[q+j] + sEB[q+j]);
          aF[rt] = v;
        }
      }
      half8 bF[4];
      #pragma unroll
      for (int ct = 0; ct < 4; ct++)
        bF[ct] = *(const half8*)(fW1T + (size_t)(colw + ct*16 + l15)*768 + kk);
      #pragma unroll
      for (int rt = 0; rt < 4; rt++)
        #pragma unroll
        for (int ct = 0; ct < 4; ct++)
          acc[rt][ct] = mfma_f16(aF[rt], bF[ct], acc[rt][ct]);
    }
    #pragma unroll
    for (int ct = 0; ct < 4; ct++){
      const int col = colw + ct*16 + l15;
      const float bb = fb1[col];
      #pragma unroll
      for (int rt = 0; rt < 4; rt++)
        #pragma unroll
        for (int ri = 0; ri < 4; ri++){
          int row = rt*16 + l4*4 + ri;
          sHid[row*264 + col] = (_Float16)fmaxf(acc[rt][ct][ri] + bb, 0.f);
        }
    }
    __syncthreads();
    #pragma unroll 1
    for (int kc = 0; kc < 8; ++kc){
      const int kk = kc*32 + l4*8;
      half8 aF[4], bF[4];
      #pragma unroll
      for (int rt = 0; rt < 4; rt++) aF[rt] = *(const half8*)(sHid + (rt*16 + l15)*264 + kk);
      #pragma unroll
      for (int ct = 0; ct < 4; ct++) bF[ct] = *(const half8*)(fW2T + (size_t)(colw + ct*16 + l15)*256 + kk);
      #pragma unroll
      for (int rt = 0; rt < 4; rt++)
        #pragma unroll
        for (int ct = 0; ct < 4; ct++)
          accM[rt][ct] = mfma_f16(aF[rt], bF[ct], accM[rt][ct]);
    }
    __syncthreads();
  }

  // ===== g branch =====
  {
    f32x4 acc[4][4];
    #pragma unroll
    for (int a_ = 0; a_ < 4; a_++)
      #pragma unroll
      for (int b_ = 0; b_ < 4; b_++) acc[a_][b_] = zf;
    #pragma unroll 1
    for (int kc = 0; kc < 24; ++kc){
      const int kk = kc*32 + l4*8;
      half8 aF[4];
      if (kc < 8){
        #pragma unroll
        for (int rt = 0; rt < 4; rt++) aF[rt] = *(const half8*)(hvf + (size_t)dd[rt]*256 + kk);
      } else if (kc < 16){
        #pragma unroll
        for (int rt = 0; rt < 4; rt++) aF[rt] = *(const half8*)(hvf + (size_t)ss[rt]*256 + (kk - 256));
      } else {
        const int q = kk - 512;
        #pragma unroll
        for (int rt = 0; rt < 4; rt++){
          half8 v;
          #pragma unroll
          for (int j = 0; j < 8; j++) v[j] = (_Float16)(ea[rt]*sEW[q+j] + sEB[q+j]);
          aF[rt] = v;
        }
      }
      half8 bF[4];
      #pragma unroll
      for (int ct = 0; ct < 4; ct++)
        bF[ct] = *(const half8*)(gW1T + (size_t)(colw + ct*16 + l15)*768 + kk);
      #pragma unroll
      for (int rt = 0; rt < 4; rt++)
        #pragma unroll
        for (int ct = 0; ct < 4; ct++)
          acc[rt][ct] = mfma_f16(aF[rt], bF[ct], acc[rt][ct]);
    }
    #pragma unroll
    for (int ct = 0; ct < 4; ct++){
      const int col = colw + ct*16 + l15;
      const float bb = gb1[col];
      #pragma unroll
      for (int rt = 0; rt < 4; rt++)
        #pragma unroll
        for (int ri = 0; ri < 4; ri++){
          int row = rt*16 + l4*4 + ri;
          sHid[row*264 + col] = (_Float16)fmaxf(acc[rt][ct][ri] + bb, 0.f);
        }
    }
    __syncthreads();
    #pragma unroll 1
    for (int kc = 0; kc < 8; ++kc){
      const int kk = kc*32 + l4*8;
      half8 aF[4], bF[4];
      #pragma unroll
      for (int rt = 0; rt < 4; rt++) aF[rt] = *(const half8*)(sHid + (rt*16 + l15)*264 + kk);
      #pragma unroll
      for (int ct = 0; ct < 4; ct++) bF[ct] = *(const half8*)(gW2T + (size_t)(colw + ct*16 + l15)*256 + kk);
      #pragma unroll
      for (int rt = 0; rt < 4; rt++)
        #pragma unroll
        for (int ct = 0; ct < 4; ct++)
          accA[rt][ct] = mfma_f16(aF[rt], bF[ct], accA[rt][ct]);
    }
    __syncthreads();
  }

  // ===== prod + segment-sum epilogue, two 32-row halves =====
  int cd = sDst[0]; float ac = 0.f;
  #pragma unroll 1
  for (int hf = 0; hf < 2; ++hf){
    #pragma unroll
    for (int ct = 0; ct < 4; ct++){
      const int col = colw + ct*16 + l15;
      const float bm = fb2[col], ba = gb2[col];
      #pragma unroll
      for (int rt2 = 0; rt2 < 2; rt2++){
        const int rt = hf*2 + rt2;
        #pragma unroll
        for (int ri = 0; ri < 4; ri++){
          int row = rt2*16 + l4*4 + ri;   // local row within half
          sProd[row*264 + col] = (accM[rt][ct][ri] + bm)*(accA[rt][ct][ri] + ba);
        }
      }
    }
    __syncthreads();
    for (int r = 0; r < 32; ++r){
      float v = sProd[r*264 + tid];
      int dr = sDst[hf*32 + r];
      if (dr != cd){ atomicAdd(&agg[(size_t)cd*256 + tid], ac); ac = 0.f; cd = dr; }
      ac += v;
    }
    __syncthreads();
  }
  atomicAdd(&agg[(size_t)cd*256 + tid], ac);
}

// ---------------- gi = [h_v, agg] @ wih^T + bih (f16 MFMA) ----------------
#define RB_GI 157
__global__ __launch_bounds__(256, 3) void gi_mfma_kernel(
    const _Float16* __restrict__ hvf, const _Float16* __restrict__ aggf,
    const _Float16* __restrict__ wihL, const float* __restrict__ bihL,
    float* __restrict__ gi)
{
  const int tid = threadIdx.x;
  const int wave = tid >> 6, lane = tid & 63, l15 = lane & 15, l4 = lane >> 4;
  const int rblk = blockIdx.x % RB_GI;
  const int cg   = blockIdx.x / RB_GI;
  const int rb = rblk*64;
  const int colw = cg*256 + wave*64;
  int rowc[4];
  #pragma unroll
  for (int rt = 0; rt < 4; rt++){ int r = rb + rt*16 + l15; rowc[rt] = (r < NN) ? r : NN-1; }
  const f32x4 zf = {0.f, 0.f, 0.f, 0.f};
  f32x4 acc[4][4];
  #pragma unroll
  for (int a_ = 0; a_ < 4; a_++)
    #pragma unroll
    for (int b_ = 0; b_ < 4; b_++) acc[a_][b_] = zf;
  #pragma unroll 1
  for (int kc = 0; kc < 16; ++kc){
    const int kk = kc*32 + l4*8;
    half8 aF[4], bF[4];
    if (kc < 8){
      #pragma unroll
      for (int rt = 0; rt < 4; rt++) aF[rt] = *(const half8*)(hvf + (size_t)rowc[rt]*256 + kk);
    } else {
      #pragma unroll
      for (int rt = 0; rt < 4; rt++) aF[rt] = *(const half8*)(aggf + (size_t)rowc[rt]*256 + (kk - 256));
    }
    #pragma unroll
    for (int ct = 0; ct < 4; ct++)
      bF[ct] = *(const half8*)(wihL + (size_t)(colw + ct*16 + l15)*512 + kk);
    #pragma unroll
    for (int rt = 0; rt < 4; rt++)
      #pragma unroll
      for (int ct = 0; ct < 4; ct++)
        acc[rt][ct] = mfma_f16(aF[rt], bF[ct], acc[rt][ct]);
  }
  #pragma unroll
  for (int ct = 0; ct < 4; ct++){
    const int col = colw + ct*16 + l15;
    const float bb = bihL[col];
    #pragma unroll
    for (int rt = 0; rt < 4; rt++)
      #pragma unroll
      for (int ri = 0; ri < 4; ri++){
        int row = rb + rt*16 + l4*4 + ri;
        if (row < NN) gi[(size_t)row*768 + col] = acc[rt][ct][ri] + bb;
      }
  }
}

// ============ GRU scan variant A (fallback): r14 scan11, 512 thr, opaque regs =========
#define FOR16(M) M(0) M(1) M(2) M(3) M(4) M(5) M(6) M(7) M(8) M(9) M(10) M(11) M(12) M(13) M(14) M(15)
#define DECL_W(i) half8 wr##i, wz##i, wn##i;
#define LD8(dst, q, i) { float4 _a = (q)[2*(i)], _b = (q)[2*(i)+1]; \
  dst[0]=(_Float16)_a.x; dst[1]=(_Float16)_a.y; dst[2]=(_Float16)_a.z; dst[3]=(_Float16)_a.w; \
  dst[4]=(_Float16)_b.x; dst[5]=(_Float16)_b.y; dst[6]=(_Float16)_b.z; dst[7]=(_Float16)_b.w; }
#define LOAD_W(i) LD8(wr##i, q0, i) LD8(wz##i, q1, i) LD8(wn##i, q2, i)
#define OPQ(i) asm volatile("" : "+v"(wr##i), "+v"(wz##i), "+v"(wn##i));
#define SV(w, a, b) __builtin_shufflevector(w, w, a, b)
#define DOT_STEP(i) { half8 hh = ph[i]; \
  half2v h0 = SV(hh, 0, 1), h1 = SV(hh, 2, 3), h2 = SV(hh, 4, 5), h3 = SV(hh, 6, 7); \
  ar0 = fdot2f(SV(wr##i, 0, 1), h0, ar0); ar1 = fdot2f(SV(wr##i, 2, 3), h1, ar1); \
  ar0 = fdot2f(SV(wr##i, 4, 5), h2, ar0); ar1 = fdot2f(SV(wr##i, 6, 7), h3, ar1); \
  az0 = fdot2f(SV(wz##i, 0, 1), h0, az0); az1 = fdot2f(SV(wz##i, 2, 3), h1, az1); \
  az0 = fdot2f(SV(wz##i, 4, 5), h2, az0); az1 = fdot2f(SV(wz##i, 6, 7), h3, az1); \
  an0 = fdot2f(SV(wn##i, 0, 1), h0, an0); an1 = fdot2f(SV(wn##i, 2, 3), h1, an1); \
  an0 = fdot2f(SV(wn##i, 4, 5), h2, an0); an1 = fdot2f(SV(wn##i, 6, 7), h3, an1); }

__global__ __launch_bounds__(512, 1) void gru_scan11(
    const float* __restrict__ whhL, const float* __restrict__ bhhL,
    const float* __restrict__ gi, float* __restrict__ hv, _Float16* __restrict__ hvf)
{
  const int t = threadIdx.x;
  const int row = t & 255;
  const int hf  = t >> 8;
  const int c0  = hf*128;
  FOR16(DECL_W)
  {
    const float4* q0 = (const float4*)(whhL + (size_t)row*256 + c0);
    const float4* q1 = (const float4*)(whhL + (size_t)(256 + row)*256 + c0);
    const float4* q2 = (const float4*)(whhL + (size_t)(512 + row)*256 + c0);
    FOR16(LOAD_W)
  }
  FOR16(OPQ)
  const float br = bhhL[row], bz = bhhL[256 + row], bn = bhhL[512 + row];
  __shared__ __align__(16) _Float16 sH16[256];
  __shared__ float sP[6][256];
  float h = 0.f;
  if (t < 256) sH16[t] = (_Float16)0.f;
  float gr = 0.f, gz = 0.f, gn = 0.f;
  if (t < 256){ gr = gi[t]; gz = gi[256 + t]; gn = gi[512 + t]; }
  __syncthreads();
  #pragma unroll 1
  for (int step = 0; step < NN; ++step){
    float pr = 0.f, pz = 0.f, pn = 0.f;
    if (t < 256){
      const float* g = gi + (size_t)((step + 1 < NN) ? step + 1 : step)*768;
      pr = g[t]; pz = g[256 + t]; pn = g[512 + t];
    }
    const half8* ph = (const half8*)(sH16 + c0);
    float ar0 = 0.f, ar1 = 0.f, az0 = 0.f, az1 = 0.f, an0 = 0.f, an1 = 0.f;
    FOR16(DOT_STEP)
    sP[0 + hf][row] = ar0 + ar1;
    sP[2 + hf][row] = az0 + az1;
    sP[4 + hf][row] = an0 + an1;
    __syncthreads();
    if (t < 256){
      float hr = sP[0][t] + sP[1][t] + br;
      float hz = sP[2][t] + sP[3][t] + bz;
      float hn = sP[4][t] + sP[5][t] + bn;
      float r = 1.f/(1.f + __expf(-(gr + hr)));
      float z = 1.f/(1.f + __expf(-(gz + hz)));
      float xx = gn + r*hn;
      xx = fminf(fmaxf(xx, -15.f), 15.f);
      float e2 = __expf(2.f*xx);
      float n = (e2 - 1.f)/(e2 + 1.f);
      h = n + z*(h - n);
      hv [(size_t)step*256 + t] = h;
      hvf[(size_t)step*256 + t] = (_Float16)h;
      sH16[t] = (_Float16)h;
      gr = pr; gz = pz; gn = pn;
    }
    __syncthreads();
  }
}

// ============ GRU scan variant B: LDS-hybrid stream (n-gate in LDS, COLUMN-MAJOR) ====
// r16 post-mortem: row-major wn layout -> wave lanes at 512B stride -> all lanes bank 0
// -> 5.12M conflicts/dispatch. Fix: COLUMN-MAJOR wnL[j*256 + row] -> a wave's 64 lanes
// (consecutive rows, same j) read consecutive 16B slots = minimal-aliasing LDS pattern.
// Waves 0..7 stream r,z (256KB/step from L2, ~0.6us at measured 427 GB/s/CU) in parallel
// with waves 8..11 reading wn from LDS (~512 clk). Same math/order as r14.
#define SVv(w, a, b) __builtin_shufflevector(w, w, a, b)
#define DOT8(w, h, acc) { \
  acc = fdot2f(SVv(w,0,1), SVv(h,0,1), acc); acc = fdot2f(SVv(w,2,3), SVv(h,2,3), acc); \
  acc = fdot2f(SVv(w,4,5), SVv(h,4,5), acc); acc = fdot2f(SVv(w,6,7), SVv(h,6,7), acc); }
#define LDPK(i) (*(const half8*)(pk + ((size_t)(i)*768 + t)*8))
#define PHASE(p, C0, C1, C2, C3, N0, N1, N2, N3) { \
  if ((p) < 7){ N0 = LDPK(4*(p)+4); N1 = LDPK(4*(p)+5); N2 = LDPK(4*(p)+6); N3 = LDPK(4*(p)+7); } \
  half8 h0 = ph[4*(p)+0], h1 = ph[4*(p)+1], h2 = ph[4*(p)+2], h3 = ph[4*(p)+3]; \
  DOT8(C0, h0, a0) DOT8(C1, h1, a1) DOT8(C2, h2, a2) DOT8(C3, h3, a3) }

__global__ __launch_bounds__(768, 1) void gru_scan14(
    const _Float16* __restrict__ pk,     // prepacked whh stream: [32][768][8] f16
    const float* __restrict__ whhL,      // raw whh layer (n-gate preload)
    const float* __restrict__ bhhL,
    const float* __restrict__ gi, float* __restrict__ hv, _Float16* __restrict__ hvf)
{
  extern __shared__ char sm[];
  half8* wnL = (half8*)sm;                               // [32][256]: wnL[j*256+row]
  float* sGH = (float*)(sm + 131072);                    // 768
  _Float16* sH16 = (_Float16*)(sm + 131072 + 3072);      // 256
  const int t = threadIdx.x;   // gate-row t
  // one-time preload of n-gate (rows 512..767), COLUMN-MAJOR: chunk (row,j) -> j*256+row
  for (int idx = t; idx < 256*32; idx += 768){
    int j = idx >> 8, row = idx & 255;
    const float* s = whhL + (size_t)(512 + row)*256 + j*8;
    half8 v;
    #pragma unroll
    for (int e = 0; e < 8; e++) v[e] = (_Float16)s[e];
    wnL[j*256 + row] = v;
  }
  const float bh = bhhL[t];
  float h = 0.f;
  if (t < 256) sH16[t] = (_Float16)0.f;
  float gr = 0.f, gz = 0.f, gn = 0.f;
  if (t < 256){ gr = gi[t]; gz = gi[256 + t]; gn = gi[512 + t]; }
  __syncthreads();
  const bool isn = (t >= 512);     // wave-uniform (waves 8..11)
  const int nrow = t - 512;
  #pragma unroll 1
  for (int step = 0; step < NN; ++step){
    float pr = 0.f, pz = 0.f, pn = 0.f;
    if (t < 256){
      const float* g = gi + (size_t)((step + 1 < NN) ? step + 1 : step)*768;
      pr = g[t]; pz = g[256 + t]; pn = g[512 + t];
    }
    const half8* ph = (const half8*)sH16;
    float a0 = 0.f, a1 = 0.f, a2 = 0.f, a3 = 0.f;
    if (!isn){
      half8 Wa0 = LDPK(0), Wa1 = LDPK(1), Wa2 = LDPK(2), Wa3 = LDPK(3);
      half8 Wb0, Wb1, Wb2, Wb3;
      PHASE(0, Wa0, Wa1, Wa2, Wa3, Wb0, Wb1, Wb2, Wb3)
      PHASE(1, Wb0, Wb1, Wb2, Wb3, Wa0, Wa1, Wa2, Wa3)
      PHASE(2, Wa0, Wa1, Wa2, Wa3, Wb0, Wb1, Wb2, Wb3)
      PHASE(3, Wb0, Wb1, Wb2, Wb3, Wa0, Wa1, Wa2, Wa3)
      PHASE(4, Wa0, Wa1, Wa2, Wa3, Wb0, Wb1, Wb2, Wb3)
      PHASE(5, Wb0, Wb1, Wb2, Wb3, Wa0, Wa1, Wa2, Wa3)
      PHASE(6, Wa0, Wa1, Wa2, Wa3, Wb0, Wb1, Wb2, Wb3)
      PHASE(7, Wb0, Wb1, Wb2, Wb3, Wa0, Wa1, Wa2, Wa3)
    } else {
      #pragma unroll
      for (int j = 0; j < 32; j += 4){
        half8 w0 = wnL[(j+0)*256 + nrow];
        half8 w1 = wnL[(j+1)*256 + nrow];
        half8 w2 = wnL[(j+2)*256 + nrow];
        half8 w3 = wnL[(j+3)*256 + nrow];
        half8 h0 = ph[j+0], h1 = ph[j+1], h2 = ph[j+2], h3 = ph[j+3];
        DOT8(w0, h0, a0) DOT8(w1, h1, a1) DOT8(w2, h2, a2) DOT8(w3, h3, a3)
      }
    }
    sGH[t] = (a0 + a1) + (a2 + a3) + bh;
    __syncthreads();
    if (t < 256){
      float hr = sGH[t], hz = sGH[256 + t], hn = sGH[512 + t];
      float r = 1.f/(1.f + __expf(-(gr + hr)));
      float z = 1.f/(1.f + __expf(-(gz + hz)));
      float xx = gn + r*hn;
      xx = fminf(fmaxf(xx, -15.f), 15.f);
      float e2 = __expf(2.f*xx);
      float n = (e2 - 1.f)/(e2 + 1.f);
      h = n + z*(h - n);
      hv [(size_t)step*256 + t] = h;
      hvf[(size_t)step*256 + t] = (_Float16)h;
      sH16[t] = (_Float16)h;
      gr = pr; gz = pz; gn = pn;
    }
    __syncthreads();
  }
}

// ---------------- heads ----------------
__global__ __launch_bounds__(256) void ge_sum_kernel(const float* __restrict__ hv, float* __restrict__ ge){
  int rb = blockIdx.x*40, t = threadIdx.x;
  float s = 0.f;
  for (int i = 0; i < 40; i++) s += hv[(size_t)(rb + i)*256 + t];
  atomicAdd(&ge[t], s);
}

__global__ void finalize_kernel(const float* __restrict__ ge, const float* __restrict__ hv,
                                const int* __restrict__ vt, float* __restrict__ gem, float* __restrict__ hvt){
  int t = threadIdx.x;
  gem[t] = ge[t]*(1.0f/NN);
  hvt[t] = hv[(size_t)vt[0]*256 + t];
}

__global__ __launch_bounds__(256) void base_np_kernel(const float* __restrict__ gem,
    const float* __restrict__ npW1, const float* __restrict__ npb1, float* __restrict__ bnp){
  __shared__ float sg[256];
  int t = threadIdx.x; sg[t] = gem[t]; __syncthreads();
  float a = npb1[t];
  for (int c = 0; c < 256; c++) a += sg[c]*npW1[c*256 + t];
  bnp[t] = a;
}

__global__ __launch_bounds__(256) void base_al_kernel(const float* __restrict__ gem,
    const float* __restrict__ hvt, const float* __restrict__ aW1,
    const float* __restrict__ ab1, float* __restrict__ bal){
  __shared__ float sg[256], sv[256];
  int t = threadIdx.x; sg[t] = gem[t]; sv[t] = hvt[t]; __syncthreads();
  float a = ab1[t];
  for (int c = 0; c < 256; c++) a += sg[c]*aW1[c*256 + t];
  for (int c = 0; c < 256; c++) a += sv[c]*aW1[(256 + c)*256 + t];
  bal[t] = a;
}

__global__ __launch_bounds__(256) void node_pred_kernel(const float* __restrict__ hv,
    const float* __restrict__ bnp, const float* __restrict__ npW1,
    const float* __restrict__ npW2, const float* __restrict__ npb2,
    float* __restrict__ outPV){
  __shared__ float sHv[16*256];
  __shared__ float sHid[16*257];
  __shared__ float sLg[16*10];
  int rb = blockIdx.x*16, t = threadIdx.x;
  for (int i = t; i < 4096; i += 256) sHv[i] = hv[(size_t)rb*256 + i];
  __syncthreads();
  float acc[16]; float b = bnp[t];
  #pragma unroll
  for (int r = 0; r < 16; r++) acc[r] = b;
  for (int c = 0; c < 256; c++){
    float w = npW1[(256 + c)*256 + t];
    #pragma unroll
    for (int r = 0; r < 16; r++) acc[r] += sHv[r*256 + c]*w;
  }
  for (int r = 0; r < 16; r++) sHid[r*257 + t] = fmaxf(acc[r], 0.f);
  __syncthreads();
  {
    int r = t >> 4, u = t & 15;
    if (u < 10){
      float a = npb2[u];
      for (int c = 0; c < 256; c++) a += sHid[r*257 + c]*npW2[c*10 + u];
      sLg[r*10 + u] = a;
    }
  }
  __syncthreads();
  if (t < 16){
    float mx = -1e30f;
    for (int u = 0; u < 10; u++) mx = fmaxf(mx, sLg[t*10 + u]);
    float s = 0.f, e[10];
    for (int u = 0; u < 10; u++){ e[u] = __expf(sLg[t*10 + u] - mx); s += e[u]; }
    float inv = 1.f/s;
    for (int u = 0; u < 10; u++) outPV[(size_t)(rb + t)*10 + u] = e[u]*inv;
  }
}

__global__ __launch_bounds__(256) void alphas_kernel(const float* __restrict__ hv,
    const float* __restrict__ bal, const float* __restrict__ aW1,
    const float* __restrict__ aW2, const float* __restrict__ ab2,
    float* __restrict__ alsum){
  __shared__ float sHv[16*256];
  __shared__ float sHid[16*257];
  __shared__ float sAv[16*20];
  int rb = blockIdx.x*16, t = threadIdx.x;
  for (int i = t; i < 4096; i += 256) sHv[i] = hv[(size_t)rb*256 + i];
  __syncthreads();
  float acc[16]; float b = bal[t];
  #pragma unroll
  for (int r = 0; r < 16; r++) acc[r] = b;
  for (int c = 0; c < 256; c++){
    float w = aW1[(512 + c)*256 + t];
    #pragma unroll
    for (int r = 0; r < 16; r++) acc[r] += sHv[r*256 + c]*w;
  }
  for (int r = 0; r < 16; r++) sHid[r*257 + t] = fmaxf(acc[r], 0.f);
  __syncthreads();
  {
    int r = t >> 4, k = t & 15;
    float a = ab2[k];
    for (int c = 0; c < 256; c++) a += sHid[r*257 + c]*aW2[c*20 + k];
    sAv[r*20 + k] = a;
    if (k < 4){
      int k2 = 16 + k;
      float a2 = ab2[k2];
      for (int c = 0; c < 256; c++) a2 += sHid[r*257 + c]*aW2[c*20 + k2];
      sAv[r*20 + k2] = a2;
    }
  }
  __syncthreads();
  if (t < 20){
    float s = 0.f;
    for (int rr = 0; rr < 16; rr++) s += sAv[rr*20 + t];
    atomicAdd(&alsum[t], s);
  }
}

__global__ void alpha_softmax_kernel(const float* __restrict__ alsum, float* __restrict__ alph){
  if (threadIdx.x == 0){
    float mx = -1e30f;
    for (int k = 0; k < 20; k++) mx = fmaxf(mx, alsum[k]);
    float s = 0.f, e[20];
    for (int k = 0; k < 20; k++){ e[k] = __expf(alsum[k] - mx); s += e[k]; }
    for (int k = 0; k < 20; k++) alph[k] = e[k]/s;
  }
}

__global__ __launch_bounds__(256) void edge_pred_kernel(const float* __restrict__ hv,
    const float* __restrict__ epW1, const float* __restrict__ epb1,
    const float* __restrict__ epW2, const float* __restrict__ epb2,
    const float* __restrict__ alph, float* __restrict__ outPE){
  __shared__ float sHv[16*256];
  __shared__ float sHid[16*257];
  __shared__ float sLT[16*100];
  __shared__ float sPE[16*5];
  __shared__ float sAl[20];
  int rb = blockIdx.x*16, t = threadIdx.x;
  for (int i = t; i < 4096; i += 256) sHv[i] = hv[(size_t)rb*256 + i];
  if (t < 20) sAl[t] = alph[t];
  if (t < 80) sPE[t] = 0.f;
  __syncthreads();
  float acc[16]; float b = epb1[t];
  #pragma unroll
  for (int r = 0; r < 16; r++) acc[r] = b;
  for (int c = 0; c < 256; c++){
    float w = epW1[c*256 + t];
    #pragma unroll
    for (int r = 0; r < 16; r++) acc[r] += sHv[r*256 + c]*w;
  }
  for (int r = 0; r < 16; r++) sHid[r*257 + t] = fmaxf(acc[r], 0.f);
  __syncthreads();
  for (int p = 0; p < 7; p++){
    int idx = p*256 + t;
    if (idx < 1600){
      int r = idx/100, j = idx%100;
      float a = epb2[j];
      for (int c = 0; c < 256; c++) a += sHid[r*257 + c]*epW2[c*100 + j];
      sLT[r*100 + j] = a;
    }
  }
  __syncthreads();
  {
    int r = t >> 4, k = t & 15;
    for (int pass = 0; pass < 2; ++pass){
      int kk = pass ? (16 + k) : k;
      if (pass && k >= 4) break;
      float lt[5];
      #pragma unroll
      for (int net = 0; net < 5; net++) lt[net] = sLT[r*100 + net*20 + kk];
      float mx = lt[0];
      #pragma unroll
      for (int net = 1; net < 5; net++) mx = fmaxf(mx, lt[net]);
      float e[5], s = 0.f;
      #pragma unroll
      for (int net = 0; net < 5; net++){ e[net] = __expf(lt[net] - mx); s += e[net]; }
      float wgt = sAl[kk]/s;
      #pragma unroll
      for (int net = 0; net < 5; net++) atomicAdd(&sPE[r*5 + net], e[net]*wgt);
    }
  }
  __syncthreads();
  if (t < 80){
    int r = t/5, net = t%5;
    outPE[(size_t)(rb + r)*5 + net] = sPE[t];
  }
}

// ---------------- launch ----------------
extern "C" void kernel_launch(void* const* d_in, const int* in_sizes, int n_in,
                              void* d_out, int out_size, void* d_ws, size_t ws_size,
                              hipStream_t stream){
  const float* x    = (const float*)d_in[0];
  const float* edge_attr = (const float*)d_in[1];
  const float* neW  = (const float*)d_in[2];
  const float* neb  = (const float*)d_in[3];
  const float* eeW  = (const float*)d_in[4];
  const float* eeb  = (const float*)d_in[5];
  const float* fW1  = (const float*)d_in[6];
  const float* fb1  = (const float*)d_in[7];
  const float* fW2  = (const float*)d_in[8];
  const float* fb2  = (const float*)d_in[9];
  const float* gW1  = (const float*)d_in[10];
  const float* gb1  = (const float*)d_in[11];
  const float* gW2  = (const float*)d_in[12];
  const float* gb2  = (const float*)d_in[13];
  const float* wih  = (const float*)d_in[14];
  const float* whh  = (const float*)d_in[15];
  const float* bih  = (const float*)d_in[16];
  const float* bhh  = (const float*)d_in[17];
  const float* aW1  = (const float*)d_in[18];
  const float* ab1  = (const float*)d_in[19];
  const float* aW2  = (const float*)d_in[20];
  const float* ab2  = (const float*)d_in[21];
  const float* npW1 = (const float*)d_in[22];
  const float* npb1 = (const float*)d_in[23];
  const float* npW2 = (const float*)d_in[24];
  const float* npb2 = (const float*)d_in[25];
  const float* epW1 = (const float*)d_in[26];
  const float* epb1 = (const float*)d_in[27];
  const float* epW2 = (const float*)d_in[28];
  const float* epb2 = (const float*)d_in[29];
  const int*   eidx = (const int*)d_in[30];
  const int*   vt   = (const int*)d_in[31];

  char* ws = (char*)d_ws;
  size_t off_ = 0;
  auto alloc = [&](size_t b){ size_t r = off_; off_ += (b + 511) & ~(size_t)511; return r; };
  float*    hv    = (float*)   (ws + alloc((size_t)NN*256*4));
  _Float16* hvf   = (_Float16*)(ws + alloc((size_t)NN*256*2));
  float*    agg   = (float*)   (ws + alloc((size_t)NN*256*4));
  _Float16* aggf  = (_Float16*)(ws + alloc((size_t)NN*256*2));
  float*    gi    = (float*)   (ws + alloc((size_t)NN*768*4));
  _Float16* fW1T  = (_Float16*)(ws + alloc((size_t)5*256*768*2));
  _Float16* gW1T  = (_Float16*)(ws + alloc((size_t)5*256*768*2));
  _Float16* fW2T  = (_Float16*)(ws + alloc((size_t)5*256*256*2));
  _Float16* gW2T  = (_Float16*)(ws + alloc((size_t)5*256*256*2));
  _Float16* wihf  = (_Float16*)(ws + alloc((size_t)5*768*512*2));
  _Float16* whhPk = (_Float16*)(ws + alloc((size_t)5*32*768*8*2));
  int*      cnt   = (int*)     (ws + alloc((size_t)NN*4));
  int*      cur   = (int*)     (ws + alloc((size_t)NN*4));
  int*      srcS  = (int*)     (ws + alloc((size_t)NE*4));
  int*      dstS  = (int*)     (ws + alloc((size_t)NE*4));
  float*    eaS   = (float*)   (ws + alloc((size_t)NE*4));
  float*    ge    = (float*)   (ws + alloc(256*4));
  float*    gem   = (float*)   (ws + alloc(256*4));
  float*    hvt   = (float*)   (ws + alloc(256*4));
  float*    bnp   = (float*)   (ws + alloc(256*4));
  float*    bal   = (float*)   (ws + alloc(256*4));
  float*    alsum = (float*)   (ws + alloc(128));
  float*    alph  = (float*)   (ws + alloc(128));

  // d_out is FLOAT32: p_v [N,10] then p_e [N,5]
  float* outPV = (float*)d_out;
  float* outPE = outPV + (size_t)NN*10;

  // allow >64KB dynamic LDS for the hybrid scan (no-op if already permitted)
  (void)hipFuncSetAttribute((const void*)gru_scan14,
                            hipFuncAttributeMaxDynamicSharedMemorySize, 135168);
  (void)hipGetLastError();   // clear stale error state

  // weight prep (f16 transposed copies + prepacked whh stream)
  prep_w1t_kernel<<<3840, 256, 0, stream>>>(fW1, gW1, fW1T, gW1T);
  prep_w2t_kernel<<<1280, 256, 0, stream>>>(fW2, gW2, fW2T, gW2T);
  cast_f16_kernel<<<2048, 256, 0, stream>>>(wih, wihf, 5*768*512);
  prep_whhPk_kernel<<<480, 256, 0, stream>>>(whh, whhPk);

  // counting sort of edges by dst
  zero_f32_kernel<<<40, 256, 0, stream>>>((float*)cnt, NN);
  hist_kernel<<<625, 256, 0, stream>>>(eidx + NE, cnt);
  scan_off_kernel<<<1, 1024, 0, stream>>>(cnt, cur);
  scatter_kernel<<<625, 256, 0, stream>>>(eidx, edge_attr, cur, srcS, dstS, eaS);

  // embedding
  embed_kernel<<<625, 256, 0, stream>>>(x, neW, neb, hv, hvf);

  const size_t edge_lds = (size_t)64*264*2 + 2048 + 256;   // 36096 B
  const size_t gru_lds  = 131072 + 3072 + 512;             // 134656 B
  for (int l = 0; l < 5; ++l){
    zero_f32_kernel<<<2048, 256, 0, stream>>>(agg, NN*256);
    edge_mlp_kernel<<<2500, 256, edge_lds, stream>>>(hvf, eaS, srcS, dstS, eeW, eeb,
        fW1T + (size_t)l*256*768, fb1 + l*256, fW2T + (size_t)l*256*256, fb2 + l*256,
        gW1T + (size_t)l*256*768, gb1 + l*256, gW2T + (size_t)l*256*256, gb2 + l*256, agg);
    cast_f16_kernel<<<2048, 256, 0, stream>>>(agg, aggf, NN*256);
    gi_mfma_kernel<<<471, 256, 0, stream>>>(hvf, aggf, wihf + (size_t)l*768*512, bih + l*768, gi);
    gru_scan14<<<1, 768, gru_lds, stream>>>(whhPk + (size_t)l*32*768*8,
        whh + (size_t)l*768*256, bhh + l*768, gi, hv, hvf);
    if (hipGetLastError() != hipSuccess){
      // deterministic fallback (environment-dependent, not data-dependent)
      gru_scan11<<<1, 512, 0, stream>>>(whh + (size_t)l*768*256, bhh + l*768, gi, hv, hvf);
    }
  }

  // heads
  zero_f32_kernel<<<1, 256, 0, stream>>>(ge, 256);
  zero_f32_kernel<<<1, 64, 0, stream>>>(alsum, 32);
  ge_sum_kernel<<<250, 256, 0, stream>>>(hv, ge);
  finalize_kernel<<<1, 256, 0, stream>>>(ge, hv, vt, gem, hvt);
  base_np_kernel<<<1, 256, 0, stream>>>(gem, npW1, npb1, bnp);
  base_al_kernel<<<1, 256, 0, stream>>>(gem, hvt, aW1, ab1, bal);
  node_pred_kernel<<<625, 256, 0, stream>>>(hv, bnp, npW1, npW2, npb2, outPV);
  alphas_kernel<<<625, 256, 0, stream>>>(hv, bal, aW1, aW2, ab2, alsum);
  alpha_softmax_kernel<<<1, 64, 0, stream>>>(alsum, alph);
  edge_pred_kernel<<<625, 256, 0, stream>>>(hv, epW1, epb1, epW2, epb2, alph, outPE);
}

// Round 18
// 57761.969 us; speedup vs baseline: 2.0348x; 2.0320x over previous
//
#include <hip/hip_runtime.h>
#include <hip/hip_bf16.h>

#define NN 10000
#define NE 160000

typedef _Float16 half8 __attribute__((ext_vector_type(8)));
typedef _Float16 half2v __attribute__((ext_vector_type(2)));
typedef float f32x4 __attribute__((ext_vector_type(4)));

__device__ __forceinline__ f32x4 mfma_f16(half8 a, half8 b, f32x4 c){
  return __builtin_amdgcn_mfma_f32_16x16x32_f16(a, b, c, 0, 0, 0);
}

#if defined(__has_builtin)
#if __has_builtin(__builtin_amdgcn_fdot2)
#define HAS_FDOT2 1
#endif
#endif

__device__ __forceinline__ float fdot2f(half2v a, half2v b, float c){
#ifdef HAS_FDOT2
  return __builtin_amdgcn_fdot2(a, b, c, false);
#else
  return c + (float)a[0]*(float)b[0] + (float)a[1]*(float)b[1];
#endif
}

// ---------------- utility ----------------
__global__ void zero_f32_kernel(float* __restrict__ p, int n){
  int i = blockIdx.x*blockDim.x + threadIdx.x;
  int st = gridDim.x*blockDim.x;
  for (; i < n; i += st) p[i] = 0.f;
}

__global__ void cast_f16_kernel(const float* __restrict__ a, _Float16* __restrict__ o, int n){
  int i = blockIdx.x*blockDim.x + threadIdx.x;
  int st = gridDim.x*blockDim.x;
  for (; i < n; i += st) o[i] = (_Float16)a[i];
}

// W1: [5][768][256] -> [5][256][768] f16 (both f and g)
__global__ void prep_w1t_kernel(const float* __restrict__ f, const float* __restrict__ g,
                                _Float16* __restrict__ fT, _Float16* __restrict__ gT){
  int i = blockIdx.x*256 + threadIdx.x;
  if (i >= 5*256*768) return;
  int l = i / (256*768); int r = i % (256*768);
  int c = r / 768; int k = r % 768;
  size_t s = (size_t)l*768*256 + (size_t)k*256 + c;
  fT[i] = (_Float16)f[s]; gT[i] = (_Float16)g[s];
}
// W2: [5][256][256] -> [5][256][256]T f16
__global__ void prep_w2t_kernel(const float* __restrict__ f, const float* __restrict__ g,
                                _Float16* __restrict__ fT, _Float16* __restrict__ gT){
  int i = blockIdx.x*256 + threadIdx.x;
  if (i >= 5*256*256) return;
  int l = i / (256*256); int r = i % (256*256);
  int c = r / 256; int k = r % 256;
  size_t s = (size_t)l*256*256 + (size_t)k*256 + c;
  fT[i] = (_Float16)f[s]; gT[i] = (_Float16)g[s];
}

// ---------------- counting sort of edges by dst ----------------
__global__ void hist_kernel(const int* __restrict__ dst, int* __restrict__ cnt){
  int e = blockIdx.x*256 + threadIdx.x;
  if (e < NE) atomicAdd(&cnt[dst[e]], 1);
}

__global__ __launch_bounds__(1024) void scan_off_kernel(const int* __restrict__ cnt, int* __restrict__ cur){
  __shared__ int sA[1024];
  const int t = threadIdx.x;
  int run = 0;
  for (int ch = 0; ch < 10; ++ch){
    int idx = ch*1024 + t;
    int v = (idx < NN) ? cnt[idx] : 0;
    sA[t] = v;
    __syncthreads();
    for (int o = 1; o < 1024; o <<= 1){
      int add = (t >= o) ? sA[t-o] : 0;
      __syncthreads();
      sA[t] += add;
      __syncthreads();
    }
    if (idx < NN) cur[idx] = run + sA[t] - v;
    run += sA[1023];
    __syncthreads();
  }
}

__global__ void scatter_kernel(const int* __restrict__ eidx, const float* __restrict__ ea,
                               int* __restrict__ cur, int* __restrict__ srcS,
                               int* __restrict__ dstS, float* __restrict__ eaS){
  int e = blockIdx.x*256 + threadIdx.x;
  if (e < NE){
    int d = eidx[NE + e];
    int p = atomicAdd(&cur[d], 1);
    srcS[p] = eidx[e];
    dstS[p] = d;
    eaS[p]  = ea[e];
  }
}

// ---------------- node embedding ----------------
__global__ __launch_bounds__(256) void embed_kernel(const float* __restrict__ x,
    const float* __restrict__ neW, const float* __restrict__ neb,
    float* __restrict__ hv, _Float16* __restrict__ hvf){
  __shared__ float sx[16*64];
  int rb = blockIdx.x*16, t = threadIdx.x;
  for (int i = t; i < 16*64; i += 256) sx[i] = x[(size_t)rb*64 + i];
  __syncthreads();
  float acc[16];
  float bb = neb[t];
  #pragma unroll
  for (int r = 0; r < 16; r++) acc[r] = bb;
  for (int c = 0; c < 64; c++){
    float w = neW[c*256 + t];
    #pragma unroll
    for (int r = 0; r < 16; r++) acc[r] += sx[r*64 + c]*w;
  }
  for (int r = 0; r < 16; r++){
    hv [(size_t)(rb+r)*256 + t] = acc[r];
    hvf[(size_t)(rb+r)*256 + t] = (_Float16)acc[r];
  }
}

// ---------------- edge MLP (f16 MFMA) ----------------
__global__ __launch_bounds__(256, 2) void edge_mlp_kernel(
    const _Float16* __restrict__ hvf, const float* __restrict__ eaS,
    const int* __restrict__ srcS, const int* __restrict__ dstS,
    const float* __restrict__ eeW, const float* __restrict__ eeb,
    const _Float16* __restrict__ fW1T, const float* __restrict__ fb1,
    const _Float16* __restrict__ fW2T, const float* __restrict__ fb2,
    const _Float16* __restrict__ gW1T, const float* __restrict__ gb1,
    const _Float16* __restrict__ gW2T, const float* __restrict__ gb2,
    float* __restrict__ agg)
{
  extern __shared__ char smem[];
  _Float16* sHid = (_Float16*)smem;             // [64][264] f16
  float* sProd = (float*)smem;                  // aliases sHid: [32][264] f32
  float* sEW  = (float*)(smem + 64*264*2);      // 256
  float* sEB  = sEW + 256;
  int*   sDst = (int*)(sEB + 256);              // 64

  const int tid = threadIdx.x;
  const int wave = tid >> 6, lane = tid & 63;
  const int l15 = lane & 15, l4 = lane >> 4;
  const int eb = blockIdx.x*64;
  if (tid < 256){ sEW[tid] = eeW[tid]; sEB[tid] = eeb[tid]; }
  if (tid < 64)  sDst[tid] = dstS[eb + tid];
  int dd[4], ss[4]; float ea[4];
  #pragma unroll
  for (int rt = 0; rt < 4; rt++){
    int e = eb + rt*16 + l15;
    dd[rt] = dstS[e]; ss[rt] = srcS[e]; ea[rt] = eaS[e];
  }
  __syncthreads();
  const int colw = wave*64;
  const f32x4 zf = {0.f, 0.f, 0.f, 0.f};

  f32x4 accM[4][4], accA[4][4];
  #pragma unroll
  for (int a_ = 0; a_ < 4; a_++)
    #pragma unroll
    for (int b_ = 0; b_ < 4; b_++){ accM[a_][b_] = zf; accA[a_][b_] = zf; }

  // ===== f branch =====
  {
    f32x4 acc[4][4];
    #pragma unroll
    for (int a_ = 0; a_ < 4; a_++)
      #pragma unroll
      for (int b_ = 0; b_ < 4; b_++) acc[a_][b_] = zf;
    #pragma unroll 1
    for (int kc = 0; kc < 24; ++kc){
      const int kk = kc*32 + l4*8;
      half8 aF[4];
      if (kc < 8){
        #pragma unroll
        for (int rt = 0; rt < 4; rt++) aF[rt] = *(const half8*)(hvf + (size_t)dd[rt]*256 + kk);
      } else if (kc < 16){
        #pragma unroll
        for (int rt = 0; rt < 4; rt++) aF[rt] = *(const half8*)(hvf + (size_t)ss[rt]*256 + (kk - 256));
      } else {
        const int q = kk - 512;
        #pragma unroll
        for (int rt = 0; rt < 4; rt++){
          half8 v;
          #pragma unroll
          for (int j = 0; j < 8; j++) v[j] = (_Float16)(ea[rt]*sEW[q+j] + sEB[q+j]);
          aF[rt] = v;
        }
      }
      half8 bF[4];
      #pragma unroll
      for (int ct = 0; ct < 4; ct++)
        bF[ct] = *(const half8*)(fW1T + (size_t)(colw + ct*16 + l15)*768 + kk);
      #pragma unroll
      for (int rt = 0; rt < 4; rt++)
        #pragma unroll
        for (int ct = 0; ct < 4; ct++)
          acc[rt][ct] = mfma_f16(aF[rt], bF[ct], acc[rt][ct]);
    }
    #pragma unroll
    for (int ct = 0; ct < 4; ct++){
      const int col = colw + ct*16 + l15;
      const float bb = fb1[col];
      #pragma unroll
      for (int rt = 0; rt < 4; rt++)
        #pragma unroll
        for (int ri = 0; ri < 4; ri++){
          int row = rt*16 + l4*4 + ri;
          sHid[row*264 + col] = (_Float16)fmaxf(acc[rt][ct][ri] + bb, 0.f);
        }
    }
    __syncthreads();
    #pragma unroll 1
    for (int kc = 0; kc < 8; ++kc){
      const int kk = kc*32 + l4*8;
      half8 aF[4], bF[4];
      #pragma unroll
      for (int rt = 0; rt < 4; rt++) aF[rt] = *(const half8*)(sHid + (rt*16 + l15)*264 + kk);
      #pragma unroll
      for (int ct = 0; ct < 4; ct++) bF[ct] = *(const half8*)(fW2T + (size_t)(colw + ct*16 + l15)*256 + kk);
      #pragma unroll
      for (int rt = 0; rt < 4; rt++)
        #pragma unroll
        for (int ct = 0; ct < 4; ct++)
          accM[rt][ct] = mfma_f16(aF[rt], bF[ct], accM[rt][ct]);
    }
    __syncthreads();
  }

  // ===== g branch =====
  {
    f32x4 acc[4][4];
    #pragma unroll
    for (int a_ = 0; a_ < 4; a_++)
      #pragma unroll
      for (int b_ = 0; b_ < 4; b_++) acc[a_][b_] = zf;
    #pragma unroll 1
    for (int kc = 0; kc < 24; ++kc){
      const int kk = kc*32 + l4*8;
      half8 aF[4];
      if (kc < 8){
        #pragma unroll
        for (int rt = 0; rt < 4; rt++) aF[rt] = *(const half8*)(hvf + (size_t)dd[rt]*256 + kk);
      } else if (kc < 16){
        #pragma unroll
        for (int rt = 0; rt < 4; rt++) aF[rt] = *(const half8*)(hvf + (size_t)ss[rt]*256 + (kk - 256));
      } else {
        const int q = kk - 512;
        #pragma unroll
        for (int rt = 0; rt < 4; rt++){
          half8 v;
          #pragma unroll
          for (int j = 0; j < 8; j++) v[j] = (_Float16)(ea[rt]*sEW[q+j] + sEB[q+j]);
          aF[rt] = v;
        }
      }
      half8 bF[4];
      #pragma unroll
      for (int ct = 0; ct < 4; ct++)
        bF[ct] = *(const half8*)(gW1T + (size_t)(colw + ct*16 + l15)*768 + kk);
      #pragma unroll
      for (int rt = 0; rt < 4; rt++)
        #pragma unroll
        for (int ct = 0; ct < 4; ct++)
          acc[rt][ct] = mfma_f16(aF[rt], bF[ct], acc[rt][ct]);
    }
    #pragma unroll
    for (int ct = 0; ct < 4; ct++){
      const int col = colw + ct*16 + l15;
      const float bb = gb1[col];
      #pragma unroll
      for (int rt = 0; rt < 4; rt++)
        #pragma unroll
        for (int ri = 0; ri < 4; ri++){
          int row = rt*16 + l4*4 + ri;
          sHid[row*264 + col] = (_Float16)fmaxf(acc[rt][ct][ri] + bb, 0.f);
        }
    }
    __syncthreads();
    #pragma unroll 1
    for (int kc = 0; kc < 8; ++kc){
      const int kk = kc*32 + l4*8;
      half8 aF[4], bF[4];
      #pragma unroll
      for (int rt = 0; rt < 4; rt++) aF[rt] = *(const half8*)(sHid + (rt*16 + l15)*264 + kk);
      #pragma unroll
      for (int ct = 0; ct < 4; ct++) bF[ct] = *(const half8*)(gW2T + (size_t)(colw + ct*16 + l15)*256 + kk);
      #pragma unroll
      for (int rt = 0; rt < 4; rt++)
        #pragma unroll
        for (int ct = 0; ct < 4; ct++)
          accA[rt][ct] = mfma_f16(aF[rt], bF[ct], accA[rt][ct]);
    }
    __syncthreads();
  }

  // ===== prod + segment-sum epilogue, two 32-row halves =====
  int cd = sDst[0]; float ac = 0.f;
  #pragma unroll 1
  for (int hf = 0; hf < 2; ++hf){
    #pragma unroll
    for (int ct = 0; ct < 4; ct++){
      const int col = colw + ct*16 + l15;
      const float bm = fb2[col], ba = gb2[col];
      #pragma unroll
      for (int rt2 = 0; rt2 < 2; rt2++){
        const int rt = hf*2 + rt2;
        #pragma unroll
        for (int ri = 0; ri < 4; ri++){
          int row = rt2*16 + l4*4 + ri;   // local row within half
          sProd[row*264 + col] = (accM[rt][ct][ri] + bm)*(accA[rt][ct][ri] + ba);
        }
      }
    }
    __syncthreads();
    for (int r = 0; r < 32; ++r){
      float v = sProd[r*264 + tid];
      int dr = sDst[hf*32 + r];
      if (dr != cd){ atomicAdd(&agg[(size_t)cd*256 + tid], ac); ac = 0.f; cd = dr; }
      ac += v;
    }
    __syncthreads();
  }
  atomicAdd(&agg[(size_t)cd*256 + tid], ac);
}

// ---------------- gi = [h_v, agg] @ wih^T + bih (f16 MFMA) ----------------
#define RB_GI 157
__global__ __launch_bounds__(256, 3) void gi_mfma_kernel(
    const _Float16* __restrict__ hvf, const _Float16* __restrict__ aggf,
    const _Float16* __restrict__ wihL, const float* __restrict__ bihL,
    float* __restrict__ gi)
{
  const int tid = threadIdx.x;
  const int wave = tid >> 6, lane = tid & 63, l15 = lane & 15, l4 = lane >> 4;
  const int rblk = blockIdx.x % RB_GI;
  const int cg   = blockIdx.x / RB_GI;
  const int rb = rblk*64;
  const int colw = cg*256 + wave*64;
  int rowc[4];
  #pragma unroll
  for (int rt = 0; rt < 4; rt++){ int r = rb + rt*16 + l15; rowc[rt] = (r < NN) ? r : NN-1; }
  const f32x4 zf = {0.f, 0.f, 0.f, 0.f};
  f32x4 acc[4][4];
  #pragma unroll
  for (int a_ = 0; a_ < 4; a_++)
    #pragma unroll
    for (int b_ = 0; b_ < 4; b_++) acc[a_][b_] = zf;
  #pragma unroll 1
  for (int kc = 0; kc < 16; ++kc){
    const int kk = kc*32 + l4*8;
    half8 aF[4], bF[4];
    if (kc < 8){
      #pragma unroll
      for (int rt = 0; rt < 4; rt++) aF[rt] = *(const half8*)(hvf + (size_t)rowc[rt]*256 + kk);
    } else {
      #pragma unroll
      for (int rt = 0; rt < 4; rt++) aF[rt] = *(const half8*)(aggf + (size_t)rowc[rt]*256 + (kk - 256));
    }
    #pragma unroll
    for (int ct = 0; ct < 4; ct++)
      bF[ct] = *(const half8*)(wihL + (size_t)(colw + ct*16 + l15)*512 + kk);
    #pragma unroll
    for (int rt = 0; rt < 4; rt++)
      #pragma unroll
      for (int ct = 0; ct < 4; ct++)
        acc[rt][ct] = mfma_f16(aF[rt], bF[ct], acc[rt][ct]);
  }
  #pragma unroll
  for (int ct = 0; ct < 4; ct++){
    const int col = colw + ct*16 + l15;
    const float bb = bihL[col];
    #pragma unroll
    for (int rt = 0; rt < 4; rt++)
      #pragma unroll
      for (int ri = 0; ri < 4; ri++){
        int row = rb + rt*16 + l4*4 + ri;
        if (row < NN) gi[(size_t)row*768 + col] = acc[rt][ct][ri] + bb;
      }
  }
}

// ---------------- serial GRU scan: 512 threads, column-split, OPAQUE weights ----------
// Best measured config (r14: 57.8 ms). The GRU scan is L2-stream-bound at ~427 GB/s/CU
// (r14/r15 agree); LDS-hybrid offload is net-negative (r16/r17: 117 ms, conflict-free).
// This is the measured plateau for the serial scan on this compiler/hardware.
#define FOR16(M) M(0) M(1) M(2) M(3) M(4) M(5) M(6) M(7) M(8) M(9) M(10) M(11) M(12) M(13) M(14) M(15)

#define DECL_W(i) half8 wr##i, wz##i, wn##i;

#define LD8(dst, q, i) { float4 _a = (q)[2*(i)], _b = (q)[2*(i)+1]; \
  dst[0]=(_Float16)_a.x; dst[1]=(_Float16)_a.y; dst[2]=(_Float16)_a.z; dst[3]=(_Float16)_a.w; \
  dst[4]=(_Float16)_b.x; dst[5]=(_Float16)_b.y; dst[6]=(_Float16)_b.z; dst[7]=(_Float16)_b.w; }

#define LOAD_W(i) LD8(wr##i, q0, i) LD8(wz##i, q1, i) LD8(wn##i, q2, i)

#define OPQ(i) asm volatile("" : "+v"(wr##i), "+v"(wz##i), "+v"(wn##i));

#define SV(w, a, b) __builtin_shufflevector(w, w, a, b)

#define DOT_STEP(i) { half8 hh = ph[i]; \
  half2v h0 = SV(hh, 0, 1), h1 = SV(hh, 2, 3), h2 = SV(hh, 4, 5), h3 = SV(hh, 6, 7); \
  ar0 = fdot2f(SV(wr##i, 0, 1), h0, ar0); ar1 = fdot2f(SV(wr##i, 2, 3), h1, ar1); \
  ar0 = fdot2f(SV(wr##i, 4, 5), h2, ar0); ar1 = fdot2f(SV(wr##i, 6, 7), h3, ar1); \
  az0 = fdot2f(SV(wz##i, 0, 1), h0, az0); az1 = fdot2f(SV(wz##i, 2, 3), h1, az1); \
  az0 = fdot2f(SV(wz##i, 4, 5), h2, az0); az1 = fdot2f(SV(wz##i, 6, 7), h3, az1); \
  an0 = fdot2f(SV(wn##i, 0, 1), h0, an0); an1 = fdot2f(SV(wn##i, 2, 3), h1, an1); \
  an0 = fdot2f(SV(wn##i, 4, 5), h2, an0); an1 = fdot2f(SV(wn##i, 6, 7), h3, an1); }

__global__ __launch_bounds__(512, 1) void gru_scan11(
    const float* __restrict__ whhL, const float* __restrict__ bhhL,
    const float* __restrict__ gi, float* __restrict__ hv, _Float16* __restrict__ hvf)
{
  const int t = threadIdx.x;
  const int row = t & 255;
  const int hf  = t >> 8;
  const int c0  = hf*128;
  FOR16(DECL_W)
  {
    const float4* q0 = (const float4*)(whhL + (size_t)row*256 + c0);
    const float4* q1 = (const float4*)(whhL + (size_t)(256 + row)*256 + c0);
    const float4* q2 = (const float4*)(whhL + (size_t)(512 + row)*256 + c0);
    FOR16(LOAD_W)
  }
  FOR16(OPQ)
  const float br = bhhL[row], bz = bhhL[256 + row], bn = bhhL[512 + row];
  __shared__ __align__(16) _Float16 sH16[256];
  __shared__ float sP[6][256];    // [gate*2+half][row]
  float h = 0.f;
  if (t < 256) sH16[t] = (_Float16)0.f;
  float gr = 0.f, gz = 0.f, gn = 0.f;
  if (t < 256){ gr = gi[t]; gz = gi[256 + t]; gn = gi[512 + t]; }
  __syncthreads();
  #pragma unroll 1
  for (int step = 0; step < NN; ++step){
    // prefetch next node's gi (hidden under dot latency)
    float pr = 0.f, pz = 0.f, pn = 0.f;
    if (t < 256){
      const float* g = gi + (size_t)((step + 1 < NN) ? step + 1 : step)*768;
      pr = g[t]; pz = g[256 + t]; pn = g[512 + t];
    }
    const half8* ph = (const half8*)(sH16 + c0);   // wave-uniform LDS reads (broadcast)
    float ar0 = 0.f, ar1 = 0.f, az0 = 0.f, az1 = 0.f, an0 = 0.f, an1 = 0.f;
    FOR16(DOT_STEP)
    sP[0 + hf][row] = ar0 + ar1;
    sP[2 + hf][row] = az0 + az1;
    sP[4 + hf][row] = an0 + an1;
    __syncthreads();
    if (t < 256){
      float hr = sP[0][t] + sP[1][t] + br;
      float hz = sP[2][t] + sP[3][t] + bz;
      float hn = sP[4][t] + sP[5][t] + bn;
      float r = 1.f/(1.f + __expf(-(gr + hr)));
      float z = 1.f/(1.f + __expf(-(gz + hz)));
      float xx = gn + r*hn;
      xx = fminf(fmaxf(xx, -15.f), 15.f);
      float e2 = __expf(2.f*xx);
      float n = (e2 - 1.f)/(e2 + 1.f);
      h = n + z*(h - n);
      hv [(size_t)step*256 + t] = h;
      hvf[(size_t)step*256 + t] = (_Float16)h;
      sH16[t] = (_Float16)h;
      gr = pr; gz = pz; gn = pn;
    }
    __syncthreads();
  }
}

// ---------------- heads ----------------
__global__ __launch_bounds__(256) void ge_sum_kernel(const float* __restrict__ hv, float* __restrict__ ge){
  int rb = blockIdx.x*40, t = threadIdx.x;
  float s = 0.f;
  for (int i = 0; i < 40; i++) s += hv[(size_t)(rb + i)*256 + t];
  atomicAdd(&ge[t], s);
}

__global__ void finalize_kernel(const float* __restrict__ ge, const float* __restrict__ hv,
                                const int* __restrict__ vt, float* __restrict__ gem, float* __restrict__ hvt){
  int t = threadIdx.x;
  gem[t] = ge[t]*(1.0f/NN);
  hvt[t] = hv[(size_t)vt[0]*256 + t];
}

__global__ __launch_bounds__(256) void base_np_kernel(const float* __restrict__ gem,
    const float* __restrict__ npW1, const float* __restrict__ npb1, float* __restrict__ bnp){
  __shared__ float sg[256];
  int t = threadIdx.x; sg[t] = gem[t]; __syncthreads();
  float a = npb1[t];
  for (int c = 0; c < 256; c++) a += sg[c]*npW1[c*256 + t];
  bnp[t] = a;
}

__global__ __launch_bounds__(256) void base_al_kernel(const float* __restrict__ gem,
    const float* __restrict__ hvt, const float* __restrict__ aW1,
    const float* __restrict__ ab1, float* __restrict__ bal){
  __shared__ float sg[256], sv[256];
  int t = threadIdx.x; sg[t] = gem[t]; sv[t] = hvt[t]; __syncthreads();
  float a = ab1[t];
  for (int c = 0; c < 256; c++) a += sg[c]*aW1[c*256 + t];
  for (int c = 0; c < 256; c++) a += sv[c]*aW1[(256 + c)*256 + t];
  bal[t] = a;
}

__global__ __launch_bounds__(256) void node_pred_kernel(const float* __restrict__ hv,
    const float* __restrict__ bnp, const float* __restrict__ npW1,
    const float* __restrict__ npW2, const float* __restrict__ npb2,
    float* __restrict__ outPV){
  __shared__ float sHv[16*256];
  __shared__ float sHid[16*257];
  __shared__ float sLg[16*10];
  int rb = blockIdx.x*16, t = threadIdx.x;
  for (int i = t; i < 4096; i += 256) sHv[i] = hv[(size_t)rb*256 + i];
  __syncthreads();
  float acc[16]; float b = bnp[t];
  #pragma unroll
  for (int r = 0; r < 16; r++) acc[r] = b;
  for (int c = 0; c < 256; c++){
    float w = npW1[(256 + c)*256 + t];
    #pragma unroll
    for (int r = 0; r < 16; r++) acc[r] += sHv[r*256 + c]*w;
  }
  for (int r = 0; r < 16; r++) sHid[r*257 + t] = fmaxf(acc[r], 0.f);
  __syncthreads();
  {
    int r = t >> 4, u = t & 15;
    if (u < 10){
      float a = npb2[u];
      for (int c = 0; c < 256; c++) a += sHid[r*257 + c]*npW2[c*10 + u];
      sLg[r*10 + u] = a;
    }
  }
  __syncthreads();
  if (t < 16){
    float mx = -1e30f;
    for (int u = 0; u < 10; u++) mx = fmaxf(mx, sLg[t*10 + u]);
    float s = 0.f, e[10];
    for (int u = 0; u < 10; u++){ e[u] = __expf(sLg[t*10 + u] - mx); s += e[u]; }
    float inv = 1.f/s;
    for (int u = 0; u < 10; u++) outPV[(size_t)(rb + t)*10 + u] = e[u]*inv;
  }
}

__global__ __launch_bounds__(256) void alphas_kernel(const float* __restrict__ hv,
    const float* __restrict__ bal, const float* __restrict__ aW1,
    const float* __restrict__ aW2, const float* __restrict__ ab2,
    float* __restrict__ alsum){
  __shared__ float sHv[16*256];
  __shared__ float sHid[16*257];
  __shared__ float sAv[16*20];
  int rb = blockIdx.x*16, t = threadIdx.x;
  for (int i = t; i < 4096; i += 256) sHv[i] = hv[(size_t)rb*256 + i];
  __syncthreads();
  float acc[16]; float b = bal[t];
  #pragma unroll
  for (int r = 0; r < 16; r++) acc[r] = b;
  for (int c = 0; c < 256; c++){
    float w = aW1[(512 + c)*256 + t];
    #pragma unroll
    for (int r = 0; r < 16; r++) acc[r] += sHv[r*256 + c]*w;
  }
  for (int r = 0; r < 16; r++) sHid[r*257 + t] = fmaxf(acc[r], 0.f);
  __syncthreads();
  {
    int r = t >> 4, k = t & 15;
    float a = ab2[k];
    for (int c = 0; c < 256; c++) a += sHid[r*257 + c]*aW2[c*20 + k];
    sAv[r*20 + k] = a;
    if (k < 4){
      int k2 = 16 + k;
      float a2 = ab2[k2];
      for (int c = 0; c < 256; c++) a2 += sHid[r*257 + c]*aW2[c*20 + k2];
      sAv[r*20 + k2] = a2;
    }
  }
  __syncthreads();
  if (t < 20){
    float s = 0.f;
    for (int rr = 0; rr < 16; rr++) s += sAv[rr*20 + t];
    atomicAdd(&alsum[t], s);
  }
}

__global__ void alpha_softmax_kernel(const float* __restrict__ alsum, float* __restrict__ alph){
  if (threadIdx.x == 0){
    float mx = -1e30f;
    for (int k = 0; k < 20; k++) mx = fmaxf(mx, alsum[k]);
    float s = 0.f, e[20];
    for (int k = 0; k < 20; k++){ e[k] = __expf(alsum[k] - mx); s += e[k]; }
    for (int k = 0; k < 20; k++) alph[k] = e[k]/s;
  }
}

__global__ __launch_bounds__(256) void edge_pred_kernel(const float* __restrict__ hv,
    const float* __restrict__ epW1, const float* __restrict__ epb1,
    const float* __restrict__ epW2, const float* __restrict__ epb2,
    const float* __restrict__ alph, float* __restrict__ outPE){
  __shared__ float sHv[16*256];
  __shared__ float sHid[16*257];
  __shared__ float sLT[16*100];
  __shared__ float sPE[16*5];
  __shared__ float sAl[20];
  int rb = blockIdx.x*16, t = threadIdx.x;
  for (int i = t; i < 4096; i += 256) sHv[i] = hv[(size_t)rb*256 + i];
  if (t < 20) sAl[t] = alph[t];
  if (t < 80) sPE[t] = 0.f;
  __syncthreads();
  float acc[16]; float b = epb1[t];
  #pragma unroll
  for (int r = 0; r < 16; r++) acc[r] = b;
  for (int c = 0; c < 256; c++){
    float w = epW1[c*256 + t];
    #pragma unroll
    for (int r = 0; r < 16; r++) acc[r] += sHv[r*256 + c]*w;
  }
  for (int r = 0; r < 16; r++) sHid[r*257 + t] = fmaxf(acc[r], 0.f);
  __syncthreads();
  for (int p = 0; p < 7; p++){
    int idx = p*256 + t;
    if (idx < 1600){
      int r = idx/100, j = idx%100;
      float a = epb2[j];
      for (int c = 0; c < 256; c++) a += sHid[r*257 + c]*epW2[c*100 + j];
      sLT[r*100 + j] = a;
    }
  }
  __syncthreads();
  {
    int r = t >> 4, k = t & 15;
    for (int pass = 0; pass < 2; ++pass){
      int kk = pass ? (16 + k) : k;
      if (pass && k >= 4) break;
      float lt[5];
      #pragma unroll
      for (int net = 0; net < 5; net++) lt[net] = sLT[r*100 + net*20 + kk];
      float mx = lt[0];
      #pragma unroll
      for (int net = 1; net < 5; net++) mx = fmaxf(mx, lt[net]);
      float e[5], s = 0.f;
      #pragma unroll
      for (int net = 0; net < 5; net++){ e[net] = __expf(lt[net] - mx); s += e[net]; }
      float wgt = sAl[kk]/s;
      #pragma unroll
      for (int net = 0; net < 5; net++) atomicAdd(&sPE[r*5 + net], e[net]*wgt);
    }
  }
  __syncthreads();
  if (t < 80){
    int r = t/5, net = t%5;
    outPE[(size_t)(rb + r)*5 + net] = sPE[t];
  }
}

// ---------------- launch ----------------
extern "C" void kernel_launch(void* const* d_in, const int* in_sizes, int n_in,
                              void* d_out, int out_size, void* d_ws, size_t ws_size,
                              hipStream_t stream){
  const float* x    = (const float*)d_in[0];
  const float* edge_attr = (const float*)d_in[1];
  const float* neW  = (const float*)d_in[2];
  const float* neb  = (const float*)d_in[3];
  const float* eeW  = (const float*)d_in[4];
  const float* eeb  = (const float*)d_in[5];
  const float* fW1  = (const float*)d_in[6];
  const float* fb1  = (const float*)d_in[7];
  const float* fW2  = (const float*)d_in[8];
  const float* fb2  = (const float*)d_in[9];
  const float* gW1  = (const float*)d_in[10];
  const float* gb1  = (const float*)d_in[11];
  const float* gW2  = (const float*)d_in[12];
  const float* gb2  = (const float*)d_in[13];
  const float* wih  = (const float*)d_in[14];
  const float* whh  = (const float*)d_in[15];
  const float* bih  = (const float*)d_in[16];
  const float* bhh  = (const float*)d_in[17];
  const float* aW1  = (const float*)d_in[18];
  const float* ab1  = (const float*)d_in[19];
  const float* aW2  = (const float*)d_in[20];
  const float* ab2  = (const float*)d_in[21];
  const float* npW1 = (const float*)d_in[22];
  const float* npb1 = (const float*)d_in[23];
  const float* npW2 = (const float*)d_in[24];
  const float* npb2 = (const float*)d_in[25];
  const float* epW1 = (const float*)d_in[26];
  const float* epb1 = (const float*)d_in[27];
  const float* epW2 = (const float*)d_in[28];
  const float* epb2 = (const float*)d_in[29];
  const int*   eidx = (const int*)d_in[30];
  const int*   vt   = (const int*)d_in[31];

  char* ws = (char*)d_ws;
  size_t off_ = 0;
  auto alloc = [&](size_t b){ size_t r = off_; off_ += (b + 511) & ~(size_t)511; return r; };
  float*    hv    = (float*)   (ws + alloc((size_t)NN*256*4));
  _Float16* hvf   = (_Float16*)(ws + alloc((size_t)NN*256*2));
  float*    agg   = (float*)   (ws + alloc((size_t)NN*256*4));
  _Float16* aggf  = (_Float16*)(ws + alloc((size_t)NN*256*2));
  float*    gi    = (float*)   (ws + alloc((size_t)NN*768*4));
  _Float16* fW1T  = (_Float16*)(ws + alloc((size_t)5*256*768*2));
  _Float16* gW1T  = (_Float16*)(ws + alloc((size_t)5*256*768*2));
  _Float16* fW2T  = (_Float16*)(ws + alloc((size_t)5*256*256*2));
  _Float16* gW2T  = (_Float16*)(ws + alloc((size_t)5*256*256*2));
  _Float16* wihf  = (_Float16*)(ws + alloc((size_t)5*768*512*2));
  int*      cnt   = (int*)     (ws + alloc((size_t)NN*4));
  int*      cur   = (int*)     (ws + alloc((size_t)NN*4));
  int*      srcS  = (int*)     (ws + alloc((size_t)NE*4));
  int*      dstS  = (int*)     (ws + alloc((size_t)NE*4));
  float*    eaS   = (float*)   (ws + alloc((size_t)NE*4));
  float*    ge    = (float*)   (ws + alloc(256*4));
  float*    gem   = (float*)   (ws + alloc(256*4));
  float*    hvt   = (float*)   (ws + alloc(256*4));
  float*    bnp   = (float*)   (ws + alloc(256*4));
  float*    bal   = (float*)   (ws + alloc(256*4));
  float*    alsum = (float*)   (ws + alloc(128));
  float*    alph  = (float*)   (ws + alloc(128));

  // d_out is FLOAT32: p_v [N,10] then p_e [N,5]
  float* outPV = (float*)d_out;
  float* outPE = outPV + (size_t)NN*10;

  // weight prep (f16 transposed copies)
  prep_w1t_kernel<<<3840, 256, 0, stream>>>(fW1, gW1, fW1T, gW1T);
  prep_w2t_kernel<<<1280, 256, 0, stream>>>(fW2, gW2, fW2T, gW2T);
  cast_f16_kernel<<<2048, 256, 0, stream>>>(wih, wihf, 5*768*512);

  // counting sort of edges by dst
  zero_f32_kernel<<<40, 256, 0, stream>>>((float*)cnt, NN);
  hist_kernel<<<625, 256, 0, stream>>>(eidx + NE, cnt);
  scan_off_kernel<<<1, 1024, 0, stream>>>(cnt, cur);
  scatter_kernel<<<625, 256, 0, stream>>>(eidx, edge_attr, cur, srcS, dstS, eaS);

  // embedding
  embed_kernel<<<625, 256, 0, stream>>>(x, neW, neb, hv, hvf);

  const size_t edge_lds = (size_t)64*264*2 + 2048 + 256;   // 36096 B
  for (int l = 0; l < 5; ++l){
    zero_f32_kernel<<<2048, 256, 0, stream>>>(agg, NN*256);
    edge_mlp_kernel<<<2500, 256, edge_lds, stream>>>(hvf, eaS, srcS, dstS, eeW, eeb,
        fW1T + (size_t)l*256*768, fb1 + l*256, fW2T + (size_t)l*256*256, fb2 + l*256,
        gW1T + (size_t)l*256*768, gb1 + l*256, gW2T + (size_t)l*256*256, gb2 + l*256, agg);
    cast_f16_kernel<<<2048, 256, 0, stream>>>(agg, aggf, NN*256);
    gi_mfma_kernel<<<471, 256, 0, stream>>>(hvf, aggf, wihf + (size_t)l*768*512, bih + l*768, gi);
    gru_scan11<<<1, 512, 0, stream>>>(whh + (size_t)l*768*256, bhh + l*768, gi, hv, hvf);
  }

  // heads
  zero_f32_kernel<<<1, 256, 0, stream>>>(ge, 256);
  zero_f32_kernel<<<1, 64, 0, stream>>>(alsum, 32);
  ge_sum_kernel<<<250, 256, 0, stream>>>(hv, ge);
  finalize_kernel<<<1, 256, 0, stream>>>(ge, hv, vt, gem, hvt);
  base_np_kernel<<<1, 256, 0, stream>>>(gem, npW1, npb1, bnp);
  base_al_kernel<<<1, 256, 0, stream>>>(gem, hvt, aW1, ab1, bal);
  node_pred_kernel<<<625, 256, 0, stream>>>(hv, bnp, npW1, npW2, npb2, outPV);
  alphas_kernel<<<625, 256, 0, stream>>>(hv, bal, aW1, aW2, ab2, alsum);
  alpha_softmax_kernel<<<1, 64, 0, stream>>>(alsum, alph);
  edge_pred_kernel<<<625, 256, 0, stream>>>(hv, epW1, epb1, epW2, epb2, alph, outPE);
}